// Round 6
// baseline (292.328 us; speedup 1.0000x reference)
//
#include <hip/hip_runtime.h>
#include <stdint.h>
#include <stddef.h>

typedef int v4i __attribute__((ext_vector_type(4)));

#define GLOAD16(gp, lp) __builtin_amdgcn_global_load_lds( \
    (const __attribute__((address_space(1))) void*)(gp),  \
    (__attribute__((address_space(3))) void*)(lp), 16, 0, 0)

#define PH_BAR()     __builtin_amdgcn_s_barrier()
#define WAIT_VM(n)   asm volatile("s_waitcnt vmcnt(" #n ")" ::: "memory")
#define SCHED_FENCE() __builtin_amdgcn_sched_barrier(0)
#define PRIO1() __builtin_amdgcn_s_setprio(1)
#define PRIO0() __builtin_amdgcn_s_setprio(0)

static __device__ __forceinline__ int pack4(int a, int b, int c, int d) {
    return (a & 255) | ((b & 255) << 8) | ((c & 255) << 16) | (d << 24);
}

// ---------------- pack: int32 (values in [-128,127]) -> int8, both arrays ----------------
__global__ __launch_bounds__(256) void pack2_kernel(const int* __restrict__ srcA, v4i* __restrict__ dstA, int nA,
                                                    const int* __restrict__ srcB, v4i* __restrict__ dstB, int nB) {
    int i = blockIdx.x * blockDim.x + threadIdx.x;
    const int* src; v4i* dst;
    if (i < nA) { src = srcA; dst = dstA; }
    else { i -= nA; if (i >= nB) return; src = srcB; dst = dstB; }
    const v4i* s = reinterpret_cast<const v4i*>(src) + (size_t)i * 4;
    v4i v0 = s[0], v1 = s[1], v2 = s[2], v3 = s[3];
    v4i r;
    r.x = pack4(v0.x, v0.y, v0.z, v0.w);
    r.y = pack4(v1.x, v1.y, v1.z, v1.w);
    r.z = pack4(v2.x, v2.y, v2.z, v2.w);
    r.w = pack4(v3.x, v3.y, v3.z, v3.w);
    dst[i] = r;
}

// ============ 256x256 8-phase i8 GEMM, 16x16x64 MFMA, reg-prefetch pipeline ============
// Each phase: [ds_reads for NEXT quadrant | stage 1 half-tile] -> MFMA(current quadrant,
// regs loaded LAST phase) -> barrier. LDS read latency hides under the MFMA cluster;
// compiler emits counted lgkmcnt for the old reads (no manual lgkmcnt(0) -- that would
// serialize). One barrier/phase. vmcnt(2) at P3/P7-end only (10 loads in flight peak).
// Buffer audit: every LDS region has >=2 barriers between last-read and overwrite-stage:
//   buf0-A last read P1 (afB-E), staged P3/P4 (AE''); buf0-B last read P1 (bf2-E),
//   staged P5/P6; buf1-A last read P5 (afB-O), staged P7/P8; buf1-B last read P5
//   (bf2-O), staged P1'/P2'.
__global__ __launch_bounds__(512, 2) void gemm_q8_8ph(
    const char* __restrict__ Apk, const char* __restrict__ Bpk,
    const int* __restrict__ bias, const float* __restrict__ wscale,
    const float* __restrict__ is_p, const float* __restrict__ os_p,
    const int* __restrict__ zp_p,
    int* __restrict__ out, int K, int Ncols)
{
    __shared__ char lds[131072];

    const int tid  = threadIdx.x;
    const int wid  = tid >> 6;
    const int lane = tid & 63;
    const int l7 = lane & 7, l3 = lane >> 3;
    const int lo16 = lane & 15, hi = lane >> 4;

    // bijective XCD-aware swizzle (m204)
    int swz;
    {
        const int nwg = gridDim.x;
        const int q = nwg >> 3, r = nwg & 7;
        const int xcd = blockIdx.x & 7;
        const int base = (xcd < r) ? xcd * (q + 1) : r * (q + 1) + (xcd - r) * q;
        swz = base + (blockIdx.x >> 3);
    }
    const int nbc  = Ncols >> 8;
    const int brow = swz / nbc, bcol = swz % nbc;

    const int wr = wid >> 2, wc = wid & 3;

    // staging: wave wid covers rows wid*8+l3 (+64 for 2nd gload, +128*h); src pre-swizzled
    const char* Ab = Apk + (size_t)(brow * 256 + wid * 8 + l3) * K + ((l7 ^ l3) << 4);
    const char* Bb = Bpk + (size_t)(bcol * 256 + wid * 8 + l3) * K + ((l7 ^ l3) << 4);

    // fragment reads: row = blockrow + lo16, col = slice*64 + hi*16, chunk ^= (row&7)
    const int colsw0 = (hi << 4) ^ (l7 << 4);
    const int colsw1 = colsw0 ^ 64;
    const int aRow = ((wr << 7) + lo16) << 7;   // (wr*128+lo16)*128
    const int bRow = ((wc << 6) + lo16) << 7;   // (wc*64+lo16)*128

    v4i acc[8][4];
#pragma unroll
    for (int m = 0; m < 8; ++m)
#pragma unroll
        for (int n = 0; n < 4; ++n)
            acc[m][n] = (v4i){0, 0, 0, 0};

    // register double-buffered fragments: afA = mh0 rows (acc 0..3), afB = mh1 (acc 4..7)
    // bfA = n01 cols (acc cols 0..1), bf2 = n23 (cols 2..3)
    v4i afA[4][2], afB[4][2], bfA[2][2], bf2[2][2];

    auto stage = [&](const char* gb, int ldsOp, int bufo, int h, int t) {
        const char* g = gb + (size_t)(h * 128) * K + ((size_t)t << 7);
        char* l = lds + (ldsOp + bufo + (h << 14) + (wid << 10));
        GLOAD16(g, l);
        GLOAD16(g + (size_t)64 * K, l + 8192);
    };
    auto ldAf = [&](v4i (&dst)[4][2], int bufo, int mh) {
#pragma unroll
        for (int m = 0; m < 4; ++m) {
            const int base = bufo + aRow + (mh << 13) + (m << 11);
            dst[m][0] = *(const v4i*)(lds + base + colsw0);
            dst[m][1] = *(const v4i*)(lds + base + colsw1);
        }
    };
    auto ldBf = [&](v4i (&dst)[2][2], int bufo, int n0) {
#pragma unroll
        for (int n = 0; n < 2; ++n) {
            const int base = 65536 + bufo + bRow + ((n0 + n) << 11);
            dst[n][0] = *(const v4i*)(lds + base + colsw0);
            dst[n][1] = *(const v4i*)(lds + base + colsw1);
        }
    };

#define MQ(afX, bfX, mo, no) do {                                                 \
    _Pragma("unroll") for (int m_ = 0; m_ < 4; ++m_)                              \
    _Pragma("unroll") for (int n_ = 0; n_ < 2; ++n_)                              \
    _Pragma("unroll") for (int s_ = 0; s_ < 2; ++s_)                              \
        acc[(mo) + m_][(no) + n_] = __builtin_amdgcn_mfma_i32_16x16x64_i8(        \
            afX[m_][s_], bfX[n_][s_], acc[(mo) + m_][(no) + n_], 0, 0, 0);        \
} while (0)

    // ---- prologue: stage tile0 A+B (buf0) + tile1 A (buf1); preload Q1-even regs ----
    stage(Ab, 0,     0,     0, 0);  stage(Ab, 0,     0,     1, 0);   // AE0
    stage(Bb, 65536, 0,     0, 0);  stage(Bb, 65536, 0,     1, 0);   // BE0
    stage(Ab, 0,     32768, 0, 1);  stage(Ab, 0,     32768, 1, 1);   // AO0
    WAIT_VM(4);           // tile0 landed; AO0 (4 loads) outstanding
    PH_BAR();
    SCHED_FENCE();
    ldAf(afA, 0, 0);      // even mh0
    ldBf(bfA, 0, 0);      // even n01

    const int niter = K >> 8;   // 2 K-tiles (256 B of K) per iteration
    for (int i = 0; i < niter - 1; ++i) {
        const int tO = 2 * i + 1, tE2 = 2 * i + 2, tO2 = 2 * i + 3;

        // P1: MFMA Q1-E (afA,bfA) | reads: bf2-E, afB-E [12] | stage BO h0
        SCHED_FENCE();
        ldBf(bf2, 0, 2);
        ldAf(afB, 0, 1);
        stage(Bb, 65536, 32768, 0, tO);
        SCHED_FENCE();
        PRIO1(); MQ(afA, bfA, 0, 0); PRIO0();
        PH_BAR();
        // P2: MFMA Q2-E (afA,bf2) | stage BO h1
        SCHED_FENCE();
        stage(Bb, 65536, 32768, 1, tO);
        SCHED_FENCE();
        PRIO1(); MQ(afA, bf2, 0, 2); PRIO0();
        PH_BAR();
        // P3: MFMA Q3-E (afB,bfA) | stage AE'' h0 | vmcnt(2): drain buf1 (AO+BO)
        SCHED_FENCE();
        stage(Ab, 0, 0, 0, tE2);
        SCHED_FENCE();
        PRIO1(); MQ(afB, bfA, 4, 0); PRIO0();
        WAIT_VM(2);
        PH_BAR();
        // P4: MFMA Q4-E (afB,bf2) | reads: afA-O, bfA-O [12] | stage AE'' h1
        SCHED_FENCE();
        ldAf(afA, 32768, 0);
        ldBf(bfA, 32768, 0);
        stage(Ab, 0, 0, 1, tE2);
        SCHED_FENCE();
        PRIO1(); MQ(afB, bf2, 4, 2); PRIO0();
        PH_BAR();
        // P5: MFMA Q1-O (afA,bfA) | reads: bf2-O, afB-O [12] | stage BE'' h0
        SCHED_FENCE();
        ldBf(bf2, 32768, 2);
        ldAf(afB, 32768, 1);
        stage(Bb, 65536, 0, 0, tE2);
        SCHED_FENCE();
        PRIO1(); MQ(afA, bfA, 0, 0); PRIO0();
        PH_BAR();
        // P6: MFMA Q2-O (afA,bf2) | stage BE'' h1
        SCHED_FENCE();
        stage(Bb, 65536, 0, 1, tE2);
        SCHED_FENCE();
        PRIO1(); MQ(afA, bf2, 0, 2); PRIO0();
        PH_BAR();
        // P7: MFMA Q3-O (afB,bfA) | stage AO'' h0 | vmcnt(2): drain buf0 (AE''+BE'')
        SCHED_FENCE();
        stage(Ab, 0, 32768, 0, tO2);
        SCHED_FENCE();
        PRIO1(); MQ(afB, bfA, 4, 0); PRIO0();
        WAIT_VM(2);
        PH_BAR();
        // P8: MFMA Q4-O (afB,bf2) | reads: afA-E'', bfA-E'' [12] | stage AO'' h1
        SCHED_FENCE();
        ldAf(afA, 0, 0);
        ldBf(bfA, 0, 0);
        stage(Ab, 0, 32768, 1, tO2);
        SCHED_FENCE();
        PRIO1(); MQ(afB, bf2, 4, 2); PRIO0();
        PH_BAR();
    }

    // ---- peeled last iteration: only BO left to stage; vmcnt(0) at P3 ----
    {
        const int tO = 2 * niter - 1;
        // P1
        SCHED_FENCE();
        ldBf(bf2, 0, 2);
        ldAf(afB, 0, 1);
        stage(Bb, 65536, 32768, 0, tO);
        SCHED_FENCE();
        PRIO1(); MQ(afA, bfA, 0, 0); PRIO0();
        PH_BAR();
        // P2
        SCHED_FENCE();
        stage(Bb, 65536, 32768, 1, tO);
        SCHED_FENCE();
        PRIO1(); MQ(afA, bf2, 0, 2); PRIO0();
        PH_BAR();
        // P3: drain everything (AO from prev P7/P8 + BO from P1/P2)
        PRIO1(); MQ(afB, bfA, 4, 0); PRIO0();
        WAIT_VM(0);
        PH_BAR();
        // P4
        SCHED_FENCE();
        ldAf(afA, 32768, 0);
        ldBf(bfA, 32768, 0);
        SCHED_FENCE();
        PRIO1(); MQ(afB, bf2, 4, 2); PRIO0();
        PH_BAR();
        // P5
        SCHED_FENCE();
        ldBf(bf2, 32768, 2);
        ldAf(afB, 32768, 1);
        SCHED_FENCE();
        PRIO1(); MQ(afA, bfA, 0, 0); PRIO0();
        PH_BAR();
        // P6
        PRIO1(); MQ(afA, bf2, 0, 2); PRIO0();
        PH_BAR();
        // P7
        PRIO1(); MQ(afB, bfA, 4, 0); PRIO0();
        PH_BAR();
        // P8
        PRIO1(); MQ(afB, bf2, 4, 2); PRIO0();
    }
#undef MQ

    // ---------------- epilogue: row-major store order, scales hoisted ----------------
    const float is = *is_p, os = *os_p;
    const float zp = (float)(*zp_p);
    const int colb = (bcol << 8) + (wc << 6) + lo16;
    float sc[4]; int bv[4];
#pragma unroll
    for (int n = 0; n < 4; ++n) {
        sc[n] = is * wscale[colb + (n << 4)] / os;
        bv[n] = bias[colb + (n << 4)];
    }
#pragma unroll
    for (int m = 0; m < 8; ++m) {
#pragma unroll
        for (int j = 0; j < 4; ++j) {
            const int row = (brow << 8) + (wr << 7) + (m << 4) + (hi << 2) + j;
            int* op = out + (size_t)row * Ncols + colb;
#pragma unroll
            for (int n = 0; n < 4; ++n) {
                float f = (float)(acc[m][n][j] + bv[n]) * sc[n] + zp;
                f = rintf(f);
                f = fminf(fmaxf(f, -128.f), 127.f);
                op[n << 4] = (int)f;
            }
        }
    }
}

// ---------------- fallback 128^2 2-barrier kernel (known-correct) ----------------
template <bool PACKED>
__global__ __launch_bounds__(256) void gemm_q8(
    const void* __restrict__ Ain, const void* __restrict__ Bin,
    const int* __restrict__ bias, const float* __restrict__ wscale,
    const float* __restrict__ is_p, const float* __restrict__ os_p,
    const int* __restrict__ zp_p,
    int* __restrict__ out, int Nrows, int K, int Ncols)
{
    __shared__ char Al[128 * 64];
    __shared__ char Bl[128 * 64];

    const int tid  = threadIdx.x;
    const int wid  = tid >> 6;
    const int lane = tid & 63;

    const int nbc = Ncols / 128;
    int swz = blockIdx.x;
    if ((gridDim.x & 7) == 0) {
        const int cpx = gridDim.x >> 3;
        swz = (blockIdx.x & 7) * cpx + (blockIdx.x >> 3);
    }
    const int brow = swz / nbc;
    const int bcol = swz % nbc;
    const int wr = wid >> 1, wc = wid & 1;

    v4i acc[4][4];
#pragma unroll
    for (int m = 0; m < 4; ++m)
#pragma unroll
        for (int n = 0; n < 4; ++n)
            acc[m][n] = (v4i){0, 0, 0, 0};

    const char* Ag = nullptr;
    const char* Bg = nullptr;
    if (PACKED) {
        Ag = (const char*)Ain + (size_t)(brow * 128 + wid * 32 + (lane >> 2)) * K + (lane & 3) * 16;
        Bg = (const char*)Bin + (size_t)(bcol * 128 + wid * 32 + (lane >> 2)) * K + (lane & 3) * 16;
    }
    char* aldst = Al + wid * 2048;
    char* bldst = Bl + wid * 2048;

    const int lo16 = lane & 15, hi = lane >> 4;
    const int aoff0 = (wr * 64 + lo16) * 64 + hi * 16;
    const int boff0 = (wc * 64 + lo16) * 64 + hi * 16;

    for (int k0 = 0; k0 < K; k0 += 64) {
        if (PACKED) {
            GLOAD16(Ag + k0,          aldst);
            GLOAD16(Ag + 16 * K + k0, aldst + 1024);
            GLOAD16(Bg + k0,          bldst);
            GLOAD16(Bg + 16 * K + k0, bldst + 1024);
        } else {
            const int row = tid >> 1, half = tid & 1;
            const int* sA = (const int*)Ain + (size_t)(brow * 128 + row) * K + k0 + half * 32;
            const int* sB = (const int*)Bin + (size_t)(bcol * 128 + row) * K + k0 + half * 32;
            int pa[8], pb[8];
#pragma unroll
            for (int j = 0; j < 8; ++j) {
                v4i va = reinterpret_cast<const v4i*>(sA)[j];
                v4i vb = reinterpret_cast<const v4i*>(sB)[j];
                pa[j] = pack4(va.x, va.y, va.z, va.w);
                pb[j] = pack4(vb.x, vb.y, vb.z, vb.w);
            }
            v4i* da = (v4i*)&Al[row * 64 + half * 32];
            da[0] = (v4i){pa[0], pa[1], pa[2], pa[3]};
            da[1] = (v4i){pa[4], pa[5], pa[6], pa[7]};
            v4i* db = (v4i*)&Bl[row * 64 + half * 32];
            db[0] = (v4i){pb[0], pb[1], pb[2], pb[3]};
            db[1] = (v4i){pb[4], pb[5], pb[6], pb[7]};
        }
        __syncthreads();

        v4i afr[4], bfr[4];
#pragma unroll
        for (int m = 0; m < 4; ++m)
            afr[m] = *(const v4i*)&Al[aoff0 + m * 16 * 64];
#pragma unroll
        for (int n = 0; n < 4; ++n)
            bfr[n] = *(const v4i*)&Bl[boff0 + n * 16 * 64];
#pragma unroll
        for (int m = 0; m < 4; ++m)
#pragma unroll
            for (int n = 0; n < 4; ++n)
                acc[m][n] = __builtin_amdgcn_mfma_i32_16x16x64_i8(afr[m], bfr[n], acc[m][n], 0, 0, 0);

        __syncthreads();
    }

    const float is = *is_p;
    const float os = *os_p;
    const float zp = (float)(*zp_p);
#pragma unroll
    for (int n = 0; n < 4; ++n) {
        const int col = bcol * 128 + wc * 64 + n * 16 + lo16;
        const float sc = is * wscale[col] / os;
        const int   bv = bias[col];
#pragma unroll
        for (int m = 0; m < 4; ++m) {
            const int row0 = brow * 128 + wr * 64 + m * 16 + hi * 4;
#pragma unroll
            for (int j = 0; j < 4; ++j) {
                float f = (float)(acc[m][n][j] + bv) * sc + zp;
                f = rintf(f);
                f = fminf(fmaxf(f, -128.f), 127.f);
                out[(size_t)(row0 + j) * Ncols + col] = (int)f;
            }
        }
    }
}

extern "C" void kernel_launch(void* const* d_in, const int* in_sizes, int n_in,
                              void* d_out, int out_size, void* d_ws, size_t ws_size,
                              hipStream_t stream) {
    const int*   x32    = (const int*)d_in[0];
    const int*   w32    = (const int*)d_in[1];
    const int*   bias   = (const int*)d_in[2];
    const float* wscale = (const float*)d_in[3];
    const float* isp    = (const float*)d_in[4];
    const float* osp    = (const float*)d_in[5];
    const int*   zpp    = (const int*)d_in[6];
    int* out = (int*)d_out;

    const int OUT = in_sizes[2];            // 4096
    const int K   = in_sizes[1] / OUT;      // 4096
    const int Nr  = in_sizes[0] / K;        // 8192

    const size_t need = (size_t)Nr * K + (size_t)OUT * K;

    if (ws_size >= need) {
        char* xpk = (char*)d_ws;
        char* wpk = xpk + (size_t)Nr * K;
        const int nx16 = (Nr * K) / 16;
        const int nw16 = (OUT * K) / 16;
        pack2_kernel<<<(nx16 + nw16 + 255) / 256, 256, 0, stream>>>(
            x32, (v4i*)xpk, nx16, w32, (v4i*)wpk, nw16);
        if ((Nr & 255) == 0 && (OUT & 255) == 0 && (K & 511) == 0) {
            const int grid8 = (Nr / 256) * (OUT / 256);
            gemm_q8_8ph<<<grid8, 512, 0, stream>>>(xpk, wpk, bias, wscale, isp, osp, zpp,
                                                   out, K, OUT);
        } else {
            const int grid = (Nr / 128) * (OUT / 128);
            gemm_q8<true><<<grid, 256, 0, stream>>>(xpk, wpk, bias, wscale, isp, osp, zpp,
                                                    out, Nr, K, OUT);
        }
    } else {
        const int grid = (Nr / 128) * (OUT / 128);
        gemm_q8<false><<<grid, 256, 0, stream>>>(x32, w32, bias, wscale, isp, osp, zpp,
                                                 out, Nr, K, OUT);
    }
}

// Round 7
// 291.485 us; speedup vs baseline: 1.0029x; 1.0029x over previous
//
#include <hip/hip_runtime.h>
#include <stdint.h>
#include <stddef.h>

typedef int v4i __attribute__((ext_vector_type(4)));

#define GLOAD16(gp, lp) __builtin_amdgcn_global_load_lds( \
    (const __attribute__((address_space(1))) void*)(gp),  \
    (__attribute__((address_space(3))) void*)(lp), 16, 0, 0)

#define PH_BAR()     __builtin_amdgcn_s_barrier()
#define WAIT_VM(n)   asm volatile("s_waitcnt vmcnt(" #n ")" ::: "memory")
#define SCHED_FENCE() __builtin_amdgcn_sched_barrier(0)
#define PRIO1() __builtin_amdgcn_s_setprio(1)
#define PRIO0() __builtin_amdgcn_s_setprio(0)

static __device__ __forceinline__ int pack4(int a, int b, int c, int d) {
    return (a & 255) | ((b & 255) << 8) | ((c & 255) << 16) | (d << 24);
}

// ---------------- pack: int32 (values in [-128,127]) -> int8, both arrays ----------------
__global__ __launch_bounds__(256) void pack2_kernel(const int* __restrict__ srcA, v4i* __restrict__ dstA, int nA,
                                                    const int* __restrict__ srcB, v4i* __restrict__ dstB, int nB) {
    int i = blockIdx.x * blockDim.x + threadIdx.x;
    const int* src; v4i* dst;
    if (i < nA) { src = srcA; dst = dstA; }
    else { i -= nA; if (i >= nB) return; src = srcB; dst = dstB; }
    const v4i* s = reinterpret_cast<const v4i*>(src) + (size_t)i * 4;
    v4i v0 = s[0], v1 = s[1], v2 = s[2], v3 = s[3];
    v4i r;
    r.x = pack4(v0.x, v0.y, v0.z, v0.w);
    r.y = pack4(v1.x, v1.y, v1.z, v1.w);
    r.z = pack4(v2.x, v2.y, v2.z, v2.w);
    r.w = pack4(v3.x, v3.y, v3.z, v3.w);
    dst[i] = r;
}

// ============ 256x256 8-phase i8 GEMM, 16x16x64 MFMA, reg-prefetch pipeline ============
// Each phase: [ds_reads for NEXT quadrant | stage 1 half-tile] -> MFMA(current quadrant,
// regs loaded LAST phase) -> barrier. LDS read latency hides under the MFMA cluster.
// __launch_bounds__(512,1): VGPR cap 256 (NOT 128 -- the (512,2) cap caused r5's spill:
// WRITE_SIZE 479MB of scratch traffic at VGPR_Count=128 with ~230 live regs).
// LDS=128KiB already limits residency to 1 block/CU, so the relaxed bound costs nothing.
__global__ __launch_bounds__(512, 1) void gemm_q8_8ph(
    const char* __restrict__ Apk, const char* __restrict__ Bpk,
    const int* __restrict__ bias, const float* __restrict__ wscale,
    const float* __restrict__ is_p, const float* __restrict__ os_p,
    const int* __restrict__ zp_p,
    int* __restrict__ out, int K, int Ncols)
{
    __shared__ char lds[131072];

    const int tid  = threadIdx.x;
    const int wid  = tid >> 6;
    const int lane = tid & 63;
    const int l7 = lane & 7, l3 = lane >> 3;
    const int lo16 = lane & 15, hi = lane >> 4;

    // bijective XCD-aware swizzle (m204)
    int swz;
    {
        const int nwg = gridDim.x;
        const int q = nwg >> 3, r = nwg & 7;
        const int xcd = blockIdx.x & 7;
        const int base = (xcd < r) ? xcd * (q + 1) : r * (q + 1) + (xcd - r) * q;
        swz = base + (blockIdx.x >> 3);
    }
    const int nbc  = Ncols >> 8;
    const int brow = swz / nbc, bcol = swz % nbc;

    const int wr = wid >> 2, wc = wid & 3;

    // staging: wave wid covers rows wid*8+l3 (+64 for 2nd gload, +128*h); src pre-swizzled
    const char* Ab = Apk + (size_t)(brow * 256 + wid * 8 + l3) * K + ((l7 ^ l3) << 4);
    const char* Bb = Bpk + (size_t)(bcol * 256 + wid * 8 + l3) * K + ((l7 ^ l3) << 4);

    // fragment reads: row = blockrow + lo16, col = slice*64 + hi*16, chunk ^= (row&7)
    const int colsw0 = (hi << 4) ^ (l7 << 4);
    const int colsw1 = colsw0 ^ 64;
    const int aRow = ((wr << 7) + lo16) << 7;   // (wr*128+lo16)*128
    const int bRow = ((wc << 6) + lo16) << 7;   // (wc*64+lo16)*128

    v4i acc[8][4];
#pragma unroll
    for (int m = 0; m < 8; ++m)
#pragma unroll
        for (int n = 0; n < 4; ++n)
            acc[m][n] = (v4i){0, 0, 0, 0};

    // register double-buffered fragments: afA = mh0 rows (acc 0..3), afB = mh1 (acc 4..7)
    // bfA = n01 cols (acc cols 0..1), bf2 = n23 (cols 2..3)
    v4i afA[4][2], afB[4][2], bfA[2][2], bf2[2][2];

    auto stage = [&](const char* gb, int ldsOp, int bufo, int h, int t) {
        const char* g = gb + (size_t)(h * 128) * K + ((size_t)t << 7);
        char* l = lds + (ldsOp + bufo + (h << 14) + (wid << 10));
        GLOAD16(g, l);
        GLOAD16(g + (size_t)64 * K, l + 8192);
    };
    auto ldAf = [&](v4i (&dst)[4][2], int bufo, int mh) {
#pragma unroll
        for (int m = 0; m < 4; ++m) {
            const int base = bufo + aRow + (mh << 13) + (m << 11);
            dst[m][0] = *(const v4i*)(lds + base + colsw0);
            dst[m][1] = *(const v4i*)(lds + base + colsw1);
        }
    };
    auto ldBf = [&](v4i (&dst)[2][2], int bufo, int n0) {
#pragma unroll
        for (int n = 0; n < 2; ++n) {
            const int base = 65536 + bufo + bRow + ((n0 + n) << 11);
            dst[n][0] = *(const v4i*)(lds + base + colsw0);
            dst[n][1] = *(const v4i*)(lds + base + colsw1);
        }
    };

#define MQ(afX, bfX, mo, no) do {                                                 \
    _Pragma("unroll") for (int m_ = 0; m_ < 4; ++m_)                              \
    _Pragma("unroll") for (int n_ = 0; n_ < 2; ++n_)                              \
    _Pragma("unroll") for (int s_ = 0; s_ < 2; ++s_)                              \
        acc[(mo) + m_][(no) + n_] = __builtin_amdgcn_mfma_i32_16x16x64_i8(        \
            afX[m_][s_], bfX[n_][s_], acc[(mo) + m_][(no) + n_], 0, 0, 0);        \
} while (0)

    // ---- prologue: stage tile0 A+B (buf0) + tile1 A (buf1); preload Q1-even regs ----
    stage(Ab, 0,     0,     0, 0);  stage(Ab, 0,     0,     1, 0);   // AE0
    stage(Bb, 65536, 0,     0, 0);  stage(Bb, 65536, 0,     1, 0);   // BE0
    stage(Ab, 0,     32768, 0, 1);  stage(Ab, 0,     32768, 1, 1);   // AO0
    WAIT_VM(4);           // tile0 landed; AO0 (4 loads) outstanding
    PH_BAR();
    SCHED_FENCE();
    ldAf(afA, 0, 0);      // even mh0
    ldBf(bfA, 0, 0);      // even n01

    const int niter = K >> 8;   // 2 K-tiles (256 B of K) per iteration
    for (int i = 0; i < niter - 1; ++i) {
        const int tO = 2 * i + 1, tE2 = 2 * i + 2, tO2 = 2 * i + 3;

        // P1: MFMA Q1-E (afA,bfA) | reads: bf2-E, afB-E [12] | stage BO h0
        SCHED_FENCE();
        ldBf(bf2, 0, 2);
        ldAf(afB, 0, 1);
        stage(Bb, 65536, 32768, 0, tO);
        SCHED_FENCE();
        PRIO1(); MQ(afA, bfA, 0, 0); PRIO0();
        PH_BAR();
        // P2: MFMA Q2-E (afA,bf2) | stage BO h1
        SCHED_FENCE();
        stage(Bb, 65536, 32768, 1, tO);
        SCHED_FENCE();
        PRIO1(); MQ(afA, bf2, 0, 2); PRIO0();
        PH_BAR();
        // P3: MFMA Q3-E (afB,bfA) | stage AE'' h0 | vmcnt(2): drain buf1 (AO+BO)
        SCHED_FENCE();
        stage(Ab, 0, 0, 0, tE2);
        SCHED_FENCE();
        PRIO1(); MQ(afB, bfA, 4, 0); PRIO0();
        WAIT_VM(2);
        PH_BAR();
        // P4: MFMA Q4-E (afB,bf2) | reads: afA-O, bfA-O [12] | stage AE'' h1
        SCHED_FENCE();
        ldAf(afA, 32768, 0);
        ldBf(bfA, 32768, 0);
        stage(Ab, 0, 0, 1, tE2);
        SCHED_FENCE();
        PRIO1(); MQ(afB, bf2, 4, 2); PRIO0();
        PH_BAR();
        // P5: MFMA Q1-O (afA,bfA) | reads: bf2-O, afB-O [12] | stage BE'' h0
        SCHED_FENCE();
        ldBf(bf2, 32768, 2);
        ldAf(afB, 32768, 1);
        stage(Bb, 65536, 0, 0, tE2);
        SCHED_FENCE();
        PRIO1(); MQ(afA, bfA, 0, 0); PRIO0();
        PH_BAR();
        // P6: MFMA Q2-O (afA,bf2) | stage BE'' h1
        SCHED_FENCE();
        stage(Bb, 65536, 0, 1, tE2);
        SCHED_FENCE();
        PRIO1(); MQ(afA, bf2, 0, 2); PRIO0();
        PH_BAR();
        // P7: MFMA Q3-O (afB,bfA) | stage AO'' h0 | vmcnt(2): drain buf0 (AE''+BE'')
        SCHED_FENCE();
        stage(Ab, 0, 32768, 0, tO2);
        SCHED_FENCE();
        PRIO1(); MQ(afB, bfA, 4, 0); PRIO0();
        WAIT_VM(2);
        PH_BAR();
        // P8: MFMA Q4-O (afB,bf2) | reads: afA-E'', bfA-E'' [12] | stage AO'' h1
        SCHED_FENCE();
        ldAf(afA, 0, 0);
        ldBf(bfA, 0, 0);
        stage(Ab, 0, 32768, 1, tO2);
        SCHED_FENCE();
        PRIO1(); MQ(afB, bf2, 4, 2); PRIO0();
        PH_BAR();
    }

    // ---- peeled last iteration: only BO left to stage; vmcnt(0) at P3 ----
    {
        const int tO = 2 * niter - 1;
        // P1
        SCHED_FENCE();
        ldBf(bf2, 0, 2);
        ldAf(afB, 0, 1);
        stage(Bb, 65536, 32768, 0, tO);
        SCHED_FENCE();
        PRIO1(); MQ(afA, bfA, 0, 0); PRIO0();
        PH_BAR();
        // P2
        SCHED_FENCE();
        stage(Bb, 65536, 32768, 1, tO);
        SCHED_FENCE();
        PRIO1(); MQ(afA, bf2, 0, 2); PRIO0();
        PH_BAR();
        // P3: drain everything (AO from prev P7/P8 + BO from P1/P2)
        PRIO1(); MQ(afB, bfA, 4, 0); PRIO0();
        WAIT_VM(0);
        PH_BAR();
        // P4
        SCHED_FENCE();
        ldAf(afA, 32768, 0);
        ldBf(bfA, 32768, 0);
        SCHED_FENCE();
        PRIO1(); MQ(afB, bf2, 4, 2); PRIO0();
        PH_BAR();
        // P5
        SCHED_FENCE();
        ldBf(bf2, 32768, 2);
        ldAf(afB, 32768, 1);
        SCHED_FENCE();
        PRIO1(); MQ(afA, bfA, 0, 0); PRIO0();
        PH_BAR();
        // P6
        PRIO1(); MQ(afA, bf2, 0, 2); PRIO0();
        PH_BAR();
        // P7
        PRIO1(); MQ(afB, bfA, 4, 0); PRIO0();
        PH_BAR();
        // P8
        PRIO1(); MQ(afB, bf2, 4, 2); PRIO0();
    }
#undef MQ

    // ---------------- epilogue: row-major store order, scales hoisted ----------------
    const float is = *is_p, os = *os_p;
    const float zp = (float)(*zp_p);
    const int colb = (bcol << 8) + (wc << 6) + lo16;
    float sc[4]; int bv[4];
#pragma unroll
    for (int n = 0; n < 4; ++n) {
        sc[n] = is * wscale[colb + (n << 4)] / os;
        bv[n] = bias[colb + (n << 4)];
    }
#pragma unroll
    for (int m = 0; m < 8; ++m) {
#pragma unroll
        for (int j = 0; j < 4; ++j) {
            const int row = (brow << 8) + (wr << 7) + (m << 4) + (hi << 2) + j;
            int* op = out + (size_t)row * Ncols + colb;
#pragma unroll
            for (int n = 0; n < 4; ++n) {
                float f = (float)(acc[m][n][j] + bv[n]) * sc[n] + zp;
                f = rintf(f);
                f = fminf(fmaxf(f, -128.f), 127.f);
                op[n << 4] = (int)f;
            }
        }
    }
}

// ---------------- fallback 128^2 2-barrier kernel (known-correct) ----------------
template <bool PACKED>
__global__ __launch_bounds__(256) void gemm_q8(
    const void* __restrict__ Ain, const void* __restrict__ Bin,
    const int* __restrict__ bias, const float* __restrict__ wscale,
    const float* __restrict__ is_p, const float* __restrict__ os_p,
    const int* __restrict__ zp_p,
    int* __restrict__ out, int Nrows, int K, int Ncols)
{
    __shared__ char Al[128 * 64];
    __shared__ char Bl[128 * 64];

    const int tid  = threadIdx.x;
    const int wid  = tid >> 6;
    const int lane = tid & 63;

    const int nbc = Ncols / 128;
    int swz = blockIdx.x;
    if ((gridDim.x & 7) == 0) {
        const int cpx = gridDim.x >> 3;
        swz = (blockIdx.x & 7) * cpx + (blockIdx.x >> 3);
    }
    const int brow = swz / nbc;
    const int bcol = swz % nbc;
    const int wr = wid >> 1, wc = wid & 1;

    v4i acc[4][4];
#pragma unroll
    for (int m = 0; m < 4; ++m)
#pragma unroll
        for (int n = 0; n < 4; ++n)
            acc[m][n] = (v4i){0, 0, 0, 0};

    const char* Ag = nullptr;
    const char* Bg = nullptr;
    if (PACKED) {
        Ag = (const char*)Ain + (size_t)(brow * 128 + wid * 32 + (lane >> 2)) * K + (lane & 3) * 16;
        Bg = (const char*)Bin + (size_t)(bcol * 128 + wid * 32 + (lane >> 2)) * K + (lane & 3) * 16;
    }
    char* aldst = Al + wid * 2048;
    char* bldst = Bl + wid * 2048;

    const int lo16 = lane & 15, hi = lane >> 4;
    const int aoff0 = (wr * 64 + lo16) * 64 + hi * 16;
    const int boff0 = (wc * 64 + lo16) * 64 + hi * 16;

    for (int k0 = 0; k0 < K; k0 += 64) {
        if (PACKED) {
            GLOAD16(Ag + k0,          aldst);
            GLOAD16(Ag + 16 * K + k0, aldst + 1024);
            GLOAD16(Bg + k0,          bldst);
            GLOAD16(Bg + 16 * K + k0, bldst + 1024);
        } else {
            const int row = tid >> 1, half = tid & 1;
            const int* sA = (const int*)Ain + (size_t)(brow * 128 + row) * K + k0 + half * 32;
            const int* sB = (const int*)Bin + (size_t)(bcol * 128 + row) * K + k0 + half * 32;
            int pa[8], pb[8];
#pragma unroll
            for (int j = 0; j < 8; ++j) {
                v4i va = reinterpret_cast<const v4i*>(sA)[j];
                v4i vb = reinterpret_cast<const v4i*>(sB)[j];
                pa[j] = pack4(va.x, va.y, va.z, va.w);
                pb[j] = pack4(vb.x, vb.y, vb.z, vb.w);
            }
            v4i* da = (v4i*)&Al[row * 64 + half * 32];
            da[0] = (v4i){pa[0], pa[1], pa[2], pa[3]};
            da[1] = (v4i){pa[4], pa[5], pa[6], pa[7]};
            v4i* db = (v4i*)&Bl[row * 64 + half * 32];
            db[0] = (v4i){pb[0], pb[1], pb[2], pb[3]};
            db[1] = (v4i){pb[4], pb[5], pb[6], pb[7]};
        }
        __syncthreads();

        v4i afr[4], bfr[4];
#pragma unroll
        for (int m = 0; m < 4; ++m)
            afr[m] = *(const v4i*)&Al[aoff0 + m * 16 * 64];
#pragma unroll
        for (int n = 0; n < 4; ++n)
            bfr[n] = *(const v4i*)&Bl[boff0 + n * 16 * 64];
#pragma unroll
        for (int m = 0; m < 4; ++m)
#pragma unroll
            for (int n = 0; n < 4; ++n)
                acc[m][n] = __builtin_amdgcn_mfma_i32_16x16x64_i8(afr[m], bfr[n], acc[m][n], 0, 0, 0);

        __syncthreads();
    }

    const float is = *is_p;
    const float os = *os_p;
    const float zp = (float)(*zp_p);
#pragma unroll
    for (int n = 0; n < 4; ++n) {
        const int col = bcol * 128 + wc * 64 + n * 16 + lo16;
        const float sc = is * wscale[col] / os;
        const int   bv = bias[col];
#pragma unroll
        for (int m = 0; m < 4; ++m) {
            const int row0 = brow * 128 + wr * 64 + m * 16 + hi * 4;
#pragma unroll
            for (int j = 0; j < 4; ++j) {
                float f = (float)(acc[m][n][j] + bv) * sc + zp;
                f = rintf(f);
                f = fminf(fmaxf(f, -128.f), 127.f);
                out[(size_t)(row0 + j) * Ncols + col] = (int)f;
            }
        }
    }
}

extern "C" void kernel_launch(void* const* d_in, const int* in_sizes, int n_in,
                              void* d_out, int out_size, void* d_ws, size_t ws_size,
                              hipStream_t stream) {
    const int*   x32    = (const int*)d_in[0];
    const int*   w32    = (const int*)d_in[1];
    const int*   bias   = (const int*)d_in[2];
    const float* wscale = (const float*)d_in[3];
    const float* isp    = (const float*)d_in[4];
    const float* osp    = (const float*)d_in[5];
    const int*   zpp    = (const int*)d_in[6];
    int* out = (int*)d_out;

    const int OUT = in_sizes[2];            // 4096
    const int K   = in_sizes[1] / OUT;      // 4096
    const int Nr  = in_sizes[0] / K;        // 8192

    const size_t need = (size_t)Nr * K + (size_t)OUT * K;

    if (ws_size >= need) {
        char* xpk = (char*)d_ws;
        char* wpk = xpk + (size_t)Nr * K;
        const int nx16 = (Nr * K) / 16;
        const int nw16 = (OUT * K) / 16;
        pack2_kernel<<<(nx16 + nw16 + 255) / 256, 256, 0, stream>>>(
            x32, (v4i*)xpk, nx16, w32, (v4i*)wpk, nw16);
        if ((Nr & 255) == 0 && (OUT & 255) == 0 && (K & 511) == 0) {
            const int grid8 = (Nr / 256) * (OUT / 256);
            gemm_q8_8ph<<<grid8, 512, 0, stream>>>(xpk, wpk, bias, wscale, isp, osp, zpp,
                                                   out, K, OUT);
        } else {
            const int grid = (Nr / 128) * (OUT / 128);
            gemm_q8<true><<<grid, 256, 0, stream>>>(xpk, wpk, bias, wscale, isp, osp, zpp,
                                                    out, Nr, K, OUT);
        }
    } else {
        const int grid = (Nr / 128) * (OUT / 128);
        gemm_q8<false><<<grid, 256, 0, stream>>>(x32, w32, bias, wscale, isp, osp, zpp,
                                                 out, Nr, K, OUT);
    }
}

// Round 8
// 191.198 us; speedup vs baseline: 1.5289x; 1.5245x over previous
//
#include <hip/hip_runtime.h>
#include <stdint.h>
#include <stddef.h>

typedef int v4i __attribute__((ext_vector_type(4)));

#define GLOAD16(gp, lp) __builtin_amdgcn_global_load_lds( \
    (const __attribute__((address_space(1))) void*)(gp),  \
    (__attribute__((address_space(3))) void*)(lp), 16, 0, 0)

#define PH_BAR()     __builtin_amdgcn_s_barrier()
#define WAIT_VM(n)   asm volatile("s_waitcnt vmcnt(" #n ")" ::: "memory")
#define SCHED_FENCE() __builtin_amdgcn_sched_barrier(0)
#define PRIO1() __builtin_amdgcn_s_setprio(1)
#define PRIO0() __builtin_amdgcn_s_setprio(0)

static __device__ __forceinline__ int pack4(int a, int b, int c, int d) {
    return (a & 255) | ((b & 255) << 8) | ((c & 255) << 16) | (d << 24);
}

// ---------------- pack: int32 (values in [-128,127]) -> int8, both arrays ----------------
__global__ __launch_bounds__(256) void pack2_kernel(const int* __restrict__ srcA, v4i* __restrict__ dstA, int nA,
                                                    const int* __restrict__ srcB, v4i* __restrict__ dstB, int nB) {
    int i = blockIdx.x * blockDim.x + threadIdx.x;
    const int* src; v4i* dst;
    if (i < nA) { src = srcA; dst = dstA; }
    else { i -= nA; if (i >= nB) return; src = srcB; dst = dstB; }
    const v4i* s = reinterpret_cast<const v4i*>(src) + (size_t)i * 4;
    v4i v0 = s[0], v1 = s[1], v2 = s[2], v3 = s[3];
    v4i r;
    r.x = pack4(v0.x, v0.y, v0.z, v0.w);
    r.y = pack4(v1.x, v1.y, v1.z, v1.w);
    r.z = pack4(v2.x, v2.y, v2.z, v2.w);
    r.w = pack4(v3.x, v3.y, v3.z, v3.w);
    dst[i] = r;
}

// ============ 256x128 4-phase i8 GEMM, 16x16x64 MFMA, reg-prefetch pipeline ============
// 8 waves = 4(M) x 2(N); per-wave out 64x64 -> acc[4][4] = 64 AGPR, freeing VGPRs so the
// register pipeline FITS (r5/r6 spilled: acc=128 AGPR left only 128 VGPR under the
// structural 256 unified-regs/wave cap at 2 waves/SIMD).
// K-tile = 128B; iter = 2 K-tiles = 4 phases x 16 MFMA. Per phase: [ds_reads for NEXT
// phase | stage | MFMA(current, regs from last phase) | counted vmcnt | 1 barrier].
// LDS: A 2buf x [256][128] @0 (64KB), B 2buf x [128][128] @65536 (32KB) = 96KB.
// Swizzle: chunk16 slot = chunk ^ (row&7) (write via pre-swizzled global source).
// vmcnt queue invariant at P1 entry: [A-odd(4)]; waits vm(2)/vm(4) alternate (audited).
__global__ __launch_bounds__(512, 1) void gemm_q8_8ph(
    const char* __restrict__ Apk, const char* __restrict__ Bpk,
    const int* __restrict__ bias, const float* __restrict__ wscale,
    const float* __restrict__ is_p, const float* __restrict__ os_p,
    const int* __restrict__ zp_p,
    int* __restrict__ out, int K, int Ncols)
{
    __shared__ char lds[98304];

    const int tid  = threadIdx.x;
    const int wid  = tid >> 6;
    const int lane = tid & 63;
    const int l7 = lane & 7, l3 = lane >> 3;
    const int lo16 = lane & 15, hi = lane >> 4;

    // bijective XCD-aware swizzle (m204)
    int swz;
    {
        const int nwg = gridDim.x;
        const int q = nwg >> 3, r = nwg & 7;
        const int xcd = blockIdx.x & 7;
        const int base = (xcd < r) ? xcd * (q + 1) : r * (q + 1) + (xcd - r) * q;
        swz = base + (blockIdx.x >> 3);
    }
    const int nbc  = Ncols >> 7;                 // 128-wide col blocks
    const int brow = swz / nbc, bcol = swz % nbc;

    const int wr = wid >> 1, wc = wid & 1;       // 4M x 2N waves, 64x64 each

    // staging bases: wave wid covers rows wid*8+l3 (+64 second gload, +128*h for A)
    const char* Ab = Apk + (size_t)(brow * 256 + wid * 8 + l3) * K + ((l7 ^ l3) << 4);
    const char* Bb = Bpk + (size_t)(bcol * 128 + wid * 8 + l3) * K + ((l7 ^ l3) << 4);

    // fragment ds_read addressing: row*128 + slot*16, slot = chunk ^ (row&7); row&7 = l7
    const int colsw0 = (hi ^ l7) << 4;
    const int colsw1 = colsw0 ^ 64;              // slice 1: chunk 4+hi -> XOR 4<<4
    const int aBase = (wr << 13) + (lo16 << 7);          // A: + par + mh<<12 + m<<11
    const int bBase = 65536 + (wc << 13) + (lo16 << 7);  // B: + par + n<<11

    v4i acc[4][4];
#pragma unroll
    for (int m = 0; m < 4; ++m)
#pragma unroll
        for (int n = 0; n < 4; ++n)
            acc[m][n] = (v4i){0, 0, 0, 0};

    // pipeline fragment buffers
    v4i afA[2][2], afB[2][2], bfE[4][2], bfO[4][2];

    auto stageA = [&](int par, int h, int t) {   // par 0|32768, h 0|1, t = K-tile idx
        const char* g = Ab + (size_t)(h * 128) * K + ((size_t)t << 7);
        char* l = lds + (par + (h << 14) + (wid << 10));
        GLOAD16(g, l);
        GLOAD16(g + (size_t)64 * K, l + 8192);
    };
    auto stageB = [&](int par, int t) {          // par 0|16384
        const char* g = Bb + ((size_t)t << 7);
        char* l = lds + (65536 + par + (wid << 10));
        GLOAD16(g, l);
        GLOAD16(g + (size_t)64 * K, l + 8192);
    };
    auto ldA = [&](v4i (&dst)[2][2], int par, int mh) {
#pragma unroll
        for (int m = 0; m < 2; ++m) {
            const int base = par + aBase + (mh << 12) + (m << 11);
            dst[m][0] = *(const v4i*)(lds + base + colsw0);
            dst[m][1] = *(const v4i*)(lds + base + colsw1);
        }
    };
    auto ldB2 = [&](v4i (&dst)[4][2], int par, int n0) {
#pragma unroll
        for (int k = 0; k < 2; ++k) {
            const int n = n0 + k;
            const int base = bBase + par + (n << 11);
            dst[n][0] = *(const v4i*)(lds + base + colsw0);
            dst[n][1] = *(const v4i*)(lds + base + colsw1);
        }
    };

#define MQ(afX, bfY, mo) do {                                                     \
    _Pragma("unroll") for (int m_ = 0; m_ < 2; ++m_)                              \
    _Pragma("unroll") for (int n_ = 0; n_ < 4; ++n_)                              \
    _Pragma("unroll") for (int s_ = 0; s_ < 2; ++s_)                              \
        acc[(mo) + m_][n_] = __builtin_amdgcn_mfma_i32_16x16x64_i8(               \
            afX[m_][s_], bfY[n_][s_], acc[(mo) + m_][n_], 0, 0, 0);               \
} while (0)

    // ---- prologue: stage tile0 (A-e,B-e) + tile1 (B-o,A-o); preload P1 regs ----
    stageA(0, 0, 0);      stageA(0, 1, 0);       // A-e  (4 loads)
    stageB(0, 0);                                // B-e  (2)
    stageB(16384, 1);                            // B-o  (2)
    stageA(32768, 0, 1);  stageA(32768, 1, 1);   // A-o  (4)
    WAIT_VM(4);            // drain A-e, B-e, B-o; queue = [A-o(4)]
    PH_BAR();
    SCHED_FENCE();
    ldA(afA, 0, 0);        // E mh0
    ldB2(bfE, 0, 0);  ldB2(bfE, 0, 2);   // E all n

    const int niter = K >> 8;   // 2 K-tiles per iteration
    for (int i = 0; i < niter - 1; ++i) {
        const int tE2 = 2 * i + 2, tO2 = 2 * i + 3;

        // P1: MFMA E-mh0 | reads: afB<-E.mh1, bfO<-O.n01 | stage B-e'
        SCHED_FENCE();
        ldA(afB, 0, 1);
        ldB2(bfO, 16384, 0);
        stageB(0, tE2);
        SCHED_FENCE();
        PRIO1(); MQ(afA, bfE, 0); PRIO0();
        WAIT_VM(2);          // drain A-o (prev P4) before P2 reads it
        PH_BAR();
        // P2: MFMA E-mh1 | reads: afA<-O.mh0, bfO<-O.n23 | stage A-e'
        SCHED_FENCE();
        ldA(afA, 32768, 0);
        ldB2(bfO, 16384, 2);
        stageA(0, 0, tE2);  stageA(0, 1, tE2);
        SCHED_FENCE();
        PRIO1(); MQ(afB, bfE, 2); PRIO0();
        WAIT_VM(4);          // drain B-e' before P3 reads it
        PH_BAR();
        // P3: MFMA O-mh0 | reads: afB<-O.mh1, bfE<-E'.n01 | stage B-o'
        SCHED_FENCE();
        ldA(afB, 32768, 1);
        ldB2(bfE, 0, 0);
        stageB(16384, tO2);
        SCHED_FENCE();
        PRIO1(); MQ(afA, bfO, 0); PRIO0();
        WAIT_VM(2);          // drain A-e' before P4 reads it
        PH_BAR();
        // P4: MFMA O-mh1 | reads: afA<-E'.mh0, bfE<-E'.n23 | stage A-o'
        SCHED_FENCE();
        ldA(afA, 0, 0);
        ldB2(bfE, 0, 2);
        stageA(32768, 0, tO2);  stageA(32768, 1, tO2);
        SCHED_FENCE();
        PRIO1(); MQ(afB, bfO, 2); PRIO0();
        WAIT_VM(4);          // drain B-o' before next-P1 reads it
        PH_BAR();
    }

    // ---- peeled last iteration (no staging) ----
    {
        // P1
        SCHED_FENCE();
        ldA(afB, 0, 1);
        ldB2(bfO, 16384, 0);
        SCHED_FENCE();
        PRIO1(); MQ(afA, bfE, 0); PRIO0();
        WAIT_VM(0);          // drain last A-o
        PH_BAR();
        // P2
        SCHED_FENCE();
        ldA(afA, 32768, 0);
        ldB2(bfO, 16384, 2);
        SCHED_FENCE();
        PRIO1(); MQ(afB, bfE, 2); PRIO0();
        // P3
        SCHED_FENCE();
        ldA(afB, 32768, 1);
        SCHED_FENCE();
        PRIO1(); MQ(afA, bfO, 0); PRIO0();
        // P4
        PRIO1(); MQ(afB, bfO, 2); PRIO0();
    }
#undef MQ

    // ---------------- epilogue: row-major store order, scales hoisted ----------------
    const float is = *is_p, os = *os_p;
    const float zp = (float)(*zp_p);
    const int colb = (bcol << 7) + (wc << 6) + lo16;
    float sc[4]; int bv[4];
#pragma unroll
    for (int n = 0; n < 4; ++n) {
        sc[n] = is * wscale[colb + (n << 4)] / os;
        bv[n] = bias[colb + (n << 4)];
    }
#pragma unroll
    for (int m = 0; m < 4; ++m) {
#pragma unroll
        for (int j = 0; j < 4; ++j) {
            const int row = (brow << 8) + (wr << 6) + (m << 4) + (hi << 2) + j;
            int* op = out + (size_t)row * Ncols + colb;
#pragma unroll
            for (int n = 0; n < 4; ++n) {
                float f = (float)(acc[m][n][j] + bv[n]) * sc[n] + zp;
                f = rintf(f);
                f = fminf(fmaxf(f, -128.f), 127.f);
                op[n << 4] = (int)f;
            }
        }
    }
}

// ---------------- fallback 128^2 2-barrier kernel (known-correct) ----------------
template <bool PACKED>
__global__ __launch_bounds__(256) void gemm_q8(
    const void* __restrict__ Ain, const void* __restrict__ Bin,
    const int* __restrict__ bias, const float* __restrict__ wscale,
    const float* __restrict__ is_p, const float* __restrict__ os_p,
    const int* __restrict__ zp_p,
    int* __restrict__ out, int Nrows, int K, int Ncols)
{
    __shared__ char Al[128 * 64];
    __shared__ char Bl[128 * 64];

    const int tid  = threadIdx.x;
    const int wid  = tid >> 6;
    const int lane = tid & 63;

    const int nbc = Ncols / 128;
    int swz = blockIdx.x;
    if ((gridDim.x & 7) == 0) {
        const int cpx = gridDim.x >> 3;
        swz = (blockIdx.x & 7) * cpx + (blockIdx.x >> 3);
    }
    const int brow = swz / nbc;
    const int bcol = swz % nbc;
    const int wr = wid >> 1, wc = wid & 1;

    v4i acc[4][4];
#pragma unroll
    for (int m = 0; m < 4; ++m)
#pragma unroll
        for (int n = 0; n < 4; ++n)
            acc[m][n] = (v4i){0, 0, 0, 0};

    const char* Ag = nullptr;
    const char* Bg = nullptr;
    if (PACKED) {
        Ag = (const char*)Ain + (size_t)(brow * 128 + wid * 32 + (lane >> 2)) * K + (lane & 3) * 16;
        Bg = (const char*)Bin + (size_t)(bcol * 128 + wid * 32 + (lane >> 2)) * K + (lane & 3) * 16;
    }
    char* aldst = Al + wid * 2048;
    char* bldst = Bl + wid * 2048;

    const int lo16 = lane & 15, hi = lane >> 4;
    const int aoff0 = (wr * 64 + lo16) * 64 + hi * 16;
    const int boff0 = (wc * 64 + lo16) * 64 + hi * 16;

    for (int k0 = 0; k0 < K; k0 += 64) {
        if (PACKED) {
            GLOAD16(Ag + k0,          aldst);
            GLOAD16(Ag + 16 * K + k0, aldst + 1024);
            GLOAD16(Bg + k0,          bldst);
            GLOAD16(Bg + 16 * K + k0, bldst + 1024);
        } else {
            const int row = tid >> 1, half = tid & 1;
            const int* sA = (const int*)Ain + (size_t)(brow * 128 + row) * K + k0 + half * 32;
            const int* sB = (const int*)Bin + (size_t)(bcol * 128 + row) * K + k0 + half * 32;
            int pa[8], pb[8];
#pragma unroll
            for (int j = 0; j < 8; ++j) {
                v4i va = reinterpret_cast<const v4i*>(sA)[j];
                v4i vb = reinterpret_cast<const v4i*>(sB)[j];
                pa[j] = pack4(va.x, va.y, va.z, va.w);
                pb[j] = pack4(vb.x, vb.y, vb.z, vb.w);
            }
            v4i* da = (v4i*)&Al[row * 64 + half * 32];
            da[0] = (v4i){pa[0], pa[1], pa[2], pa[3]};
            da[1] = (v4i){pa[4], pa[5], pa[6], pa[7]};
            v4i* db = (v4i*)&Bl[row * 64 + half * 32];
            db[0] = (v4i){pb[0], pb[1], pb[2], pb[3]};
            db[1] = (v4i){pb[4], pb[5], pb[6], pb[7]};
        }
        __syncthreads();

        v4i afr[4], bfr[4];
#pragma unroll
        for (int m = 0; m < 4; ++m)
            afr[m] = *(const v4i*)&Al[aoff0 + m * 16 * 64];
#pragma unroll
        for (int n = 0; n < 4; ++n)
            bfr[n] = *(const v4i*)&Bl[boff0 + n * 16 * 64];
#pragma unroll
        for (int m = 0; m < 4; ++m)
#pragma unroll
            for (int n = 0; n < 4; ++n)
                acc[m][n] = __builtin_amdgcn_mfma_i32_16x16x64_i8(afr[m], bfr[n], acc[m][n], 0, 0, 0);

        __syncthreads();
    }

    const float is = *is_p;
    const float os = *os_p;
    const float zp = (float)(*zp_p);
#pragma unroll
    for (int n = 0; n < 4; ++n) {
        const int col = bcol * 128 + wc * 64 + n * 16 + lo16;
        const float sc = is * wscale[col] / os;
        const int   bv = bias[col];
#pragma unroll
        for (int m = 0; m < 4; ++m) {
            const int row0 = brow * 128 + wr * 64 + m * 16 + hi * 4;
#pragma unroll
            for (int j = 0; j < 4; ++j) {
                float f = (float)(acc[m][n][j] + bv) * sc + zp;
                f = rintf(f);
                f = fminf(fmaxf(f, -128.f), 127.f);
                out[(size_t)(row0 + j) * Ncols + col] = (int)f;
            }
        }
    }
}

extern "C" void kernel_launch(void* const* d_in, const int* in_sizes, int n_in,
                              void* d_out, int out_size, void* d_ws, size_t ws_size,
                              hipStream_t stream) {
    const int*   x32    = (const int*)d_in[0];
    const int*   w32    = (const int*)d_in[1];
    const int*   bias   = (const int*)d_in[2];
    const float* wscale = (const float*)d_in[3];
    const float* isp    = (const float*)d_in[4];
    const float* osp    = (const float*)d_in[5];
    const int*   zpp    = (const int*)d_in[6];
    int* out = (int*)d_out;

    const int OUT = in_sizes[2];            // 4096
    const int K   = in_sizes[1] / OUT;      // 4096
    const int Nr  = in_sizes[0] / K;        // 8192

    const size_t need = (size_t)Nr * K + (size_t)OUT * K;

    if (ws_size >= need) {
        char* xpk = (char*)d_ws;
        char* wpk = xpk + (size_t)Nr * K;
        const int nx16 = (Nr * K) / 16;
        const int nw16 = (OUT * K) / 16;
        pack2_kernel<<<(nx16 + nw16 + 255) / 256, 256, 0, stream>>>(
            x32, (v4i*)xpk, nx16, w32, (v4i*)wpk, nw16);
        if ((Nr & 255) == 0 && (OUT & 127) == 0 && (K & 255) == 0 && (K >> 8) >= 2) {
            const int grid8 = (Nr / 256) * (OUT / 128);
            gemm_q8_8ph<<<grid8, 512, 0, stream>>>(xpk, wpk, bias, wscale, isp, osp, zpp,
                                                   out, K, OUT);
        } else {
            const int grid = (Nr / 128) * (OUT / 128);
            gemm_q8<true><<<grid, 256, 0, stream>>>(xpk, wpk, bias, wscale, isp, osp, zpp,
                                                    out, Nr, K, OUT);
        }
    } else {
        const int grid = (Nr / 128) * (OUT / 128);
        gemm_q8<false><<<grid, 256, 0, stream>>>(x32, w32, bias, wscale, isp, osp, zpp,
                                                 out, Nr, K, OUT);
    }
}

// Round 9
// 177.353 us; speedup vs baseline: 1.6483x; 1.0781x over previous
//
#include <hip/hip_runtime.h>
#include <stdint.h>
#include <stddef.h>

typedef int v4i __attribute__((ext_vector_type(4)));

#define GLOAD16(gp, lp) __builtin_amdgcn_global_load_lds( \
    (const __attribute__((address_space(1))) void*)(gp),  \
    (__attribute__((address_space(3))) void*)(lp), 16, 0, 0)

#define PH_BAR()     __builtin_amdgcn_s_barrier()
#define WAIT_VM(n)   asm volatile("s_waitcnt vmcnt(" #n ")" ::: "memory")
#define SCHED_FENCE() __builtin_amdgcn_sched_barrier(0)
#define PRIO1() __builtin_amdgcn_s_setprio(1)
#define PRIO0() __builtin_amdgcn_s_setprio(0)

static __device__ __forceinline__ int pack4(int a, int b, int c, int d) {
    return (a & 255) | ((b & 255) << 8) | ((c & 255) << 16) | (d << 24);
}

// ---------------- pack: int32 (values in [-128,127]) -> int8, both arrays ----------------
__global__ __launch_bounds__(256) void pack2_kernel(const int* __restrict__ srcA, v4i* __restrict__ dstA, int nA,
                                                    const int* __restrict__ srcB, v4i* __restrict__ dstB, int nB) {
    int i = blockIdx.x * blockDim.x + threadIdx.x;
    const int* src; v4i* dst;
    if (i < nA) { src = srcA; dst = dstA; }
    else { i -= nA; if (i >= nB) return; src = srcB; dst = dstB; }
    const v4i* s = reinterpret_cast<const v4i*>(src) + (size_t)i * 4;
    v4i v0 = s[0], v1 = s[1], v2 = s[2], v3 = s[3];
    v4i r;
    r.x = pack4(v0.x, v0.y, v0.z, v0.w);
    r.y = pack4(v1.x, v1.y, v1.z, v1.w);
    r.z = pack4(v2.x, v2.y, v2.z, v2.w);
    r.w = pack4(v3.x, v3.y, v3.z, v3.w);
    dst[i] = r;
}

// ========== 256x256 m-pair-phase i8 GEMM: 4 phases/K-tile, af reg-pipeline ==========
// 8 waves = 2(M) x 4(N), per-wave out 128x64 = acc[8][4] (128 AGPR).
// Phase p of tile t = MFMA of m-pair p (2 m-frags x 4 n x 2 k-slices = 16 MFMA) using af
// regs read the PREVIOUS phase (afA/afB ping-pong, 16 VGPR each); bf[4][2] (32 VGPR)
// refreshed once per K-tile at P1 with s0-ordered MFMAs (only first half-phase waits).
// Reg budget: 128 acc + 32 af + 32 bf + addr ~= 212 < 256 unified cap (no spill).
// Staging: tile t+1 issued at t.P1 (A, 4 loads) / t.P2 (B, 4 loads), drained by
// WAIT_VM(0) at t.P3-end (2-phase landing window); earliest read of tile t+1 data is
// t.P4 (af pair0'). Write-after-read: buf[(t+1)&1] holds t-1 data, last read t-1.P3,
// staged from t.P1 -> 2 barriers between. One s_barrier per phase.
// LDS: A buf b @ b*32768 (32KB each), B @ 65536 + b*32768. Swizzle chunk16 ^= row&7
// (write via pre-swizzled global source; read via colsw) -- conflict-free (r3 PMC: 0).
__global__ __launch_bounds__(512, 1) void gemm_q8_mp(
    const char* __restrict__ Apk, const char* __restrict__ Bpk,
    const int* __restrict__ bias, const float* __restrict__ wscale,
    const float* __restrict__ is_p, const float* __restrict__ os_p,
    const int* __restrict__ zp_p,
    int* __restrict__ out, int K, int Ncols)
{
    __shared__ char lds[131072];

    const int tid  = threadIdx.x;
    const int wid  = tid >> 6;
    const int lane = tid & 63;
    const int l7 = lane & 7, l3 = lane >> 3;
    const int lo16 = lane & 15, hi = lane >> 4;

    // bijective XCD-aware swizzle (m204)
    int swz;
    {
        const int nwg = gridDim.x;
        const int q = nwg >> 3, r = nwg & 7;
        const int xcd = blockIdx.x & 7;
        const int base = (xcd < r) ? xcd * (q + 1) : r * (q + 1) + (xcd - r) * q;
        swz = base + (blockIdx.x >> 3);
    }
    const int nbc  = Ncols >> 8;
    const int brow = swz / nbc, bcol = swz % nbc;

    const int wr = wid >> 2, wc = wid & 3;   // 2M x 4N waves, 128x64 out each

    // staging bases: wave wid covers rows wid*8+l3 (+64 second gload, +128*h); pre-swizzled src
    const char* Ab = Apk + (size_t)(brow * 256 + wid * 8 + l3) * K + ((l7 ^ l3) << 4);
    const char* Bb = Bpk + (size_t)(bcol * 256 + wid * 8 + l3) * K + ((l7 ^ l3) << 4);

    // ds_read: row*128 + slot*16, slot = chunk ^ (row&7); row&7 == l7 for all frag reads
    const int colsw0 = (hi ^ l7) << 4;
    const int colsw1 = colsw0 ^ 64;
    const int aBase = (wr << 14) + (lo16 << 7);          // + buf + pair<<12 + m<<11
    const int bBase = (wc << 13) + (lo16 << 7);          // + 65536 + buf + n<<11

    v4i acc[8][4];
#pragma unroll
    for (int m = 0; m < 8; ++m)
#pragma unroll
        for (int n = 0; n < 4; ++n)
            acc[m][n] = (v4i){0, 0, 0, 0};

    v4i afA[2][2], afB[2][2], bf[4][2];

    auto stage = [&](const char* gb, int ldsOff, int h, int t) {
        const char* g = gb + (size_t)(h * 128) * K + ((size_t)t << 7);
        char* l = lds + (ldsOff + (h << 14) + (wid << 10));
        GLOAD16(g, l);
        GLOAD16(g + (size_t)64 * K, l + 8192);
    };
    auto ldAf = [&](v4i (&dst)[2][2], int bufo, int pair) {
#pragma unroll
        for (int m = 0; m < 2; ++m) {
            const int base = bufo + aBase + (pair << 12) + (m << 11);
            dst[m][0] = *(const v4i*)(lds + base + colsw0);
            dst[m][1] = *(const v4i*)(lds + base + colsw1);
        }
    };
    auto ldBf = [&](int bufo) {      // all 4 n; s0 group first (P1 MFMAs consume s0 first)
#pragma unroll
        for (int n = 0; n < 4; ++n)
            bf[n][0] = *(const v4i*)(lds + 65536 + bufo + bBase + (n << 11) + colsw0);
#pragma unroll
        for (int n = 0; n < 4; ++n)
            bf[n][1] = *(const v4i*)(lds + 65536 + bufo + bBase + (n << 11) + colsw1);
    };

    // s-OUTER: first 8 MFMAs need only bf[.][0]; dep distance 8 per acc chain
#define MQ(afX, p) do {                                                           \
    _Pragma("unroll") for (int s_ = 0; s_ < 2; ++s_)                              \
    _Pragma("unroll") for (int m_ = 0; m_ < 2; ++m_)                              \
    _Pragma("unroll") for (int n_ = 0; n_ < 4; ++n_)                              \
        acc[((p) << 1) + m_][n_] = __builtin_amdgcn_mfma_i32_16x16x64_i8(         \
            afX[m_][s_], bf[n_][s_], acc[((p) << 1) + m_][n_], 0, 0, 0);          \
} while (0)

    // ---- prologue: stage tile0 (A+B, 8 loads), drain, read afA<-pair0 ----
    stage(Ab, 0,     0, 0);  stage(Ab, 0,     1, 0);
    stage(Bb, 65536, 0, 0);  stage(Bb, 65536, 1, 0);
    WAIT_VM(0);
    PH_BAR();
    SCHED_FENCE();
    ldAf(afA, 0, 0);

    const int nt = K >> 7;    // K-tiles of 128 B
    for (int t = 0; t < nt - 1; ++t) {
        const int b  = (t & 1) << 15;
        const int nb = (~t & 1) << 15;

        // P1: MFMA pair0 (afA) | reads: bf (8, s0 first), afB<-pair1 | stage A(t+1)
        SCHED_FENCE();
        ldBf(b);
        ldAf(afB, b, 1);
        stage(Ab, nb, 0, t + 1);  stage(Ab, nb, 1, t + 1);
        SCHED_FENCE();
        PRIO1(); MQ(afA, 0); PRIO0();
        PH_BAR();
        // P2: MFMA pair1 (afB) | reads: afA<-pair2 | stage B(t+1)
        SCHED_FENCE();
        ldAf(afA, b, 2);
        stage(Bb, 65536 + nb, 0, t + 1);  stage(Bb, 65536 + nb, 1, t + 1);
        SCHED_FENCE();
        PRIO1(); MQ(afB, 1); PRIO0();
        PH_BAR();
        // P3: MFMA pair2 (afA) | reads: afB<-pair3 | drain staging (8 in flight)
        SCHED_FENCE();
        ldAf(afB, b, 3);
        SCHED_FENCE();
        PRIO1(); MQ(afA, 2); PRIO0();
        WAIT_VM(0);
        PH_BAR();
        // P4: MFMA pair3 (afB) | reads: afA<-pair0 of tile t+1 (buf nb, just drained)
        SCHED_FENCE();
        ldAf(afA, nb, 0);
        SCHED_FENCE();
        PRIO1(); MQ(afB, 3); PRIO0();
        PH_BAR();
    }

    // ---- peeled last tile (no staging) ----
    {
        const int b = ((nt - 1) & 1) << 15;
        SCHED_FENCE();
        ldBf(b);
        ldAf(afB, b, 1);
        SCHED_FENCE();
        PRIO1(); MQ(afA, 0); PRIO0();
        PH_BAR();
        SCHED_FENCE();
        ldAf(afA, b, 2);
        SCHED_FENCE();
        PRIO1(); MQ(afB, 1); PRIO0();
        PH_BAR();
        SCHED_FENCE();
        ldAf(afB, b, 3);
        SCHED_FENCE();
        PRIO1(); MQ(afA, 2); PRIO0();
        PH_BAR();
        PRIO1(); MQ(afB, 3); PRIO0();
    }
#undef MQ

    // ---------------- epilogue: row-major store order, scales hoisted ----------------
    const float is = *is_p, os = *os_p;
    const float zp = (float)(*zp_p);
    const int colb = (bcol << 8) + (wc << 6) + lo16;
    float sc[4]; int bv[4];
#pragma unroll
    for (int n = 0; n < 4; ++n) {
        sc[n] = is * wscale[colb + (n << 4)] / os;
        bv[n] = bias[colb + (n << 4)];
    }
#pragma unroll
    for (int m = 0; m < 8; ++m) {
#pragma unroll
        for (int j = 0; j < 4; ++j) {
            const int row = (brow << 8) + (wr << 7) + (m << 4) + (hi << 2) + j;
            int* op = out + (size_t)row * Ncols + colb;
#pragma unroll
            for (int n = 0; n < 4; ++n) {
                float f = (float)(acc[m][n][j] + bv[n]) * sc[n] + zp;
                f = rintf(f);
                f = fminf(fmaxf(f, -128.f), 127.f);
                op[n << 4] = (int)f;
            }
        }
    }
}

// ---------------- fallback 128^2 2-barrier kernel (known-correct) ----------------
template <bool PACKED>
__global__ __launch_bounds__(256) void gemm_q8(
    const void* __restrict__ Ain, const void* __restrict__ Bin,
    const int* __restrict__ bias, const float* __restrict__ wscale,
    const float* __restrict__ is_p, const float* __restrict__ os_p,
    const int* __restrict__ zp_p,
    int* __restrict__ out, int Nrows, int K, int Ncols)
{
    __shared__ char Al[128 * 64];
    __shared__ char Bl[128 * 64];

    const int tid  = threadIdx.x;
    const int wid  = tid >> 6;
    const int lane = tid & 63;

    const int nbc = Ncols / 128;
    int swz = blockIdx.x;
    if ((gridDim.x & 7) == 0) {
        const int cpx = gridDim.x >> 3;
        swz = (blockIdx.x & 7) * cpx + (blockIdx.x >> 3);
    }
    const int brow = swz / nbc;
    const int bcol = swz % nbc;
    const int wr = wid >> 1, wc = wid & 1;

    v4i acc[4][4];
#pragma unroll
    for (int m = 0; m < 4; ++m)
#pragma unroll
        for (int n = 0; n < 4; ++n)
            acc[m][n] = (v4i){0, 0, 0, 0};

    const char* Ag = nullptr;
    const char* Bg = nullptr;
    if (PACKED) {
        Ag = (const char*)Ain + (size_t)(brow * 128 + wid * 32 + (lane >> 2)) * K + (lane & 3) * 16;
        Bg = (const char*)Bin + (size_t)(bcol * 128 + wid * 32 + (lane >> 2)) * K + (lane & 3) * 16;
    }
    char* aldst = Al + wid * 2048;
    char* bldst = Bl + wid * 2048;

    const int lo16 = lane & 15, hi = lane >> 4;
    const int aoff0 = (wr * 64 + lo16) * 64 + hi * 16;
    const int boff0 = (wc * 64 + lo16) * 64 + hi * 16;

    for (int k0 = 0; k0 < K; k0 += 64) {
        if (PACKED) {
            GLOAD16(Ag + k0,          aldst);
            GLOAD16(Ag + 16 * K + k0, aldst + 1024);
            GLOAD16(Bg + k0,          bldst);
            GLOAD16(Bg + 16 * K + k0, bldst + 1024);
        } else {
            const int row = tid >> 1, half = tid & 1;
            const int* sA = (const int*)Ain + (size_t)(brow * 128 + row) * K + k0 + half * 32;
            const int* sB = (const int*)Bin + (size_t)(bcol * 128 + row) * K + k0 + half * 32;
            int pa[8], pb[8];
#pragma unroll
            for (int j = 0; j < 8; ++j) {
                v4i va = reinterpret_cast<const v4i*>(sA)[j];
                v4i vb = reinterpret_cast<const v4i*>(sB)[j];
                pa[j] = pack4(va.x, va.y, va.z, va.w);
                pb[j] = pack4(vb.x, vb.y, vb.z, vb.w);
            }
            v4i* da = (v4i*)&Al[row * 64 + half * 32];
            da[0] = (v4i){pa[0], pa[1], pa[2], pa[3]};
            da[1] = (v4i){pa[4], pa[5], pa[6], pa[7]};
            v4i* db = (v4i*)&Bl[row * 64 + half * 32];
            db[0] = (v4i){pb[0], pb[1], pb[2], pb[3]};
            db[1] = (v4i){pb[4], pb[5], pb[6], pb[7]};
        }
        __syncthreads();

        v4i afr[4], bfr[4];
#pragma unroll
        for (int m = 0; m < 4; ++m)
            afr[m] = *(const v4i*)&Al[aoff0 + m * 16 * 64];
#pragma unroll
        for (int n = 0; n < 4; ++n)
            bfr[n] = *(const v4i*)&Bl[boff0 + n * 16 * 64];
#pragma unroll
        for (int m = 0; m < 4; ++m)
#pragma unroll
            for (int n = 0; n < 4; ++n)
                acc[m][n] = __builtin_amdgcn_mfma_i32_16x16x64_i8(afr[m], bfr[n], acc[m][n], 0, 0, 0);

        __syncthreads();
    }

    const float is = *is_p;
    const float os = *os_p;
    const float zp = (float)(*zp_p);
#pragma unroll
    for (int n = 0; n < 4; ++n) {
        const int col = bcol * 128 + wc * 64 + n * 16 + lo16;
        const float sc = is * wscale[col] / os;
        const int   bv = bias[col];
#pragma unroll
        for (int m = 0; m < 4; ++m) {
            const int row0 = brow * 128 + wr * 64 + m * 16 + hi * 4;
#pragma unroll
            for (int j = 0; j < 4; ++j) {
                float f = (float)(acc[m][n][j] + bv) * sc + zp;
                f = rintf(f);
                f = fminf(fmaxf(f, -128.f), 127.f);
                out[(size_t)(row0 + j) * Ncols + col] = (int)f;
            }
        }
    }
}

extern "C" void kernel_launch(void* const* d_in, const int* in_sizes, int n_in,
                              void* d_out, int out_size, void* d_ws, size_t ws_size,
                              hipStream_t stream) {
    const int*   x32    = (const int*)d_in[0];
    const int*   w32    = (const int*)d_in[1];
    const int*   bias   = (const int*)d_in[2];
    const float* wscale = (const float*)d_in[3];
    const float* isp    = (const float*)d_in[4];
    const float* osp    = (const float*)d_in[5];
    const int*   zpp    = (const int*)d_in[6];
    int* out = (int*)d_out;

    const int OUT = in_sizes[2];            // 4096
    const int K   = in_sizes[1] / OUT;      // 4096
    const int Nr  = in_sizes[0] / K;        // 8192

    const size_t need = (size_t)Nr * K + (size_t)OUT * K;

    if (ws_size >= need) {
        char* xpk = (char*)d_ws;
        char* wpk = xpk + (size_t)Nr * K;
        const int nx16 = (Nr * K) / 16;
        const int nw16 = (OUT * K) / 16;
        pack2_kernel<<<(nx16 + nw16 + 255) / 256, 256, 0, stream>>>(
            x32, (v4i*)xpk, nx16, w32, (v4i*)wpk, nw16);
        if ((Nr & 255) == 0 && (OUT & 255) == 0 && (K & 127) == 0 && (K >> 7) >= 2) {
            const int grid8 = (Nr / 256) * (OUT / 256);
            gemm_q8_mp<<<grid8, 512, 0, stream>>>(xpk, wpk, bias, wscale, isp, osp, zpp,
                                                  out, K, OUT);
        } else {
            const int grid = (Nr / 128) * (OUT / 128);
            gemm_q8<true><<<grid, 256, 0, stream>>>(xpk, wpk, bias, wscale, isp, osp, zpp,
                                                    out, Nr, K, OUT);
        }
    } else {
        const int grid = (Nr / 128) * (OUT / 128);
        gemm_q8<false><<<grid, 256, 0, stream>>>(x32, w32, bias, wscale, isp, osp, zpp,
                                                 out, Nr, K, OUT);
    }
}

// Round 10
// 171.736 us; speedup vs baseline: 1.7022x; 1.0327x over previous
//
#include <hip/hip_runtime.h>
#include <stdint.h>
#include <stddef.h>

typedef int v4i __attribute__((ext_vector_type(4)));

#define GLOAD16(gp, lp) __builtin_amdgcn_global_load_lds( \
    (const __attribute__((address_space(1))) void*)(gp),  \
    (__attribute__((address_space(3))) void*)(lp), 16, 0, 0)

#define PH_BAR()     __builtin_amdgcn_s_barrier()
#define WAIT_VM(n)   asm volatile("s_waitcnt vmcnt(" #n ")" ::: "memory")
#define WAIT_LGKM0() asm volatile("s_waitcnt lgkmcnt(0)" ::: "memory")
#define SCHED_FENCE() __builtin_amdgcn_sched_barrier(0)
#define PRIO1() __builtin_amdgcn_s_setprio(1)
#define PRIO0() __builtin_amdgcn_s_setprio(0)

static __device__ __forceinline__ int pack4(int a, int b, int c, int d) {
    return (a & 255) | ((b & 255) << 8) | ((c & 255) << 16) | (d << 24);
}

// ---------------- pack: int32 (values in [-128,127]) -> int8, both arrays ----------------
__global__ __launch_bounds__(256) void pack2_kernel(const int* __restrict__ srcA, v4i* __restrict__ dstA, int nA,
                                                    const int* __restrict__ srcB, v4i* __restrict__ dstB, int nB) {
    int i = blockIdx.x * blockDim.x + threadIdx.x;
    const int* src; v4i* dst;
    if (i < nA) { src = srcA; dst = dstA; }
    else { i -= nA; if (i >= nB) return; src = srcB; dst = dstB; }
    const v4i* s = reinterpret_cast<const v4i*>(src) + (size_t)i * 4;
    v4i v0 = s[0], v1 = s[1], v2 = s[2], v3 = s[3];
    v4i r;
    r.x = pack4(v0.x, v0.y, v0.z, v0.w);
    r.y = pack4(v1.x, v1.y, v1.z, v1.w);
    r.z = pack4(v2.x, v2.y, v2.z, v2.w);
    r.w = pack4(v3.x, v3.y, v3.z, v3.w);
    dst[i] = r;
}

// ========== 256x256 i8 GEMM: ONE barrier per K-tile (de-convoyed m-pair pipeline) ==========
// Same geometry/regs as r8 (2Mx4N waves, acc[8][4]=128 AGPR, af ping-pong 32, bf 32 ->
// 244 total regs, fits the 256/wave cap at 512 threads). CHANGE vs r8: P1/P2/P4-end
// barriers removed -- buffer-hazard audit shows only the P3-end sync is required:
//   vmcnt(0): staging of tile t+1 (issued P1/P2) landed  -> P4 may read buf nb
//   lgkmcnt(0): this wave's reads of buf b retired       -> t+1's staging of b is WAR-safe
//   (staging into b is issued after this barrier, at t+1.P1)
// Without per-phase barriers the 8 waves skew; one wave's MFMA burst covers another's
// LDS read burst (setprio arbitrates) -- breaking r3/r8's measured MFMA+LDS *sum* behavior.
// Per-wave ordering inside a tile is enforced by register dependences alone:
//   MQ(afA,0) < ldAf(afA,2) (WAR) < MQ(afA,2) (RAW) < ldAf(afA,nb,0) (WAR), same for afB/bf.
__global__ __launch_bounds__(512, 1) void gemm_q8_mp(
    const char* __restrict__ Apk, const char* __restrict__ Bpk,
    const int* __restrict__ bias, const float* __restrict__ wscale,
    const float* __restrict__ is_p, const float* __restrict__ os_p,
    const int* __restrict__ zp_p,
    int* __restrict__ out, int K, int Ncols)
{
    __shared__ char lds[131072];

    const int tid  = threadIdx.x;
    const int wid  = tid >> 6;
    const int lane = tid & 63;
    const int l7 = lane & 7, l3 = lane >> 3;
    const int lo16 = lane & 15, hi = lane >> 4;

    // bijective XCD-aware swizzle (m204)
    int swz;
    {
        const int nwg = gridDim.x;
        const int q = nwg >> 3, r = nwg & 7;
        const int xcd = blockIdx.x & 7;
        const int base = (xcd < r) ? xcd * (q + 1) : r * (q + 1) + (xcd - r) * q;
        swz = base + (blockIdx.x >> 3);
    }
    const int nbc  = Ncols >> 8;
    const int brow = swz / nbc, bcol = swz % nbc;

    const int wr = wid >> 2, wc = wid & 3;   // 2M x 4N waves, 128x64 out each

    // staging bases: wave wid covers rows wid*8+l3 (+64 second gload, +128*h); pre-swizzled src
    const char* Ab = Apk + (size_t)(brow * 256 + wid * 8 + l3) * K + ((l7 ^ l3) << 4);
    const char* Bb = Bpk + (size_t)(bcol * 256 + wid * 8 + l3) * K + ((l7 ^ l3) << 4);

    // ds_read: row*128 + slot*16, slot = chunk ^ (row&7); row&7 == l7 for all frag reads
    const int colsw0 = (hi ^ l7) << 4;
    const int colsw1 = colsw0 ^ 64;
    const int aBase = (wr << 14) + (lo16 << 7);          // + buf + pair<<12 + m<<11
    const int bBase = (wc << 13) + (lo16 << 7);          // + 65536 + buf + n<<11

    v4i acc[8][4];
#pragma unroll
    for (int m = 0; m < 8; ++m)
#pragma unroll
        for (int n = 0; n < 4; ++n)
            acc[m][n] = (v4i){0, 0, 0, 0};

    v4i afA[2][2], afB[2][2], bf[4][2];

    auto stage = [&](const char* gb, int ldsOff, int h, int t) {
        const char* g = gb + (size_t)(h * 128) * K + ((size_t)t << 7);
        char* l = lds + (ldsOff + (h << 14) + (wid << 10));
        GLOAD16(g, l);
        GLOAD16(g + (size_t)64 * K, l + 8192);
    };
    auto ldAf = [&](v4i (&dst)[2][2], int bufo, int pair) {
#pragma unroll
        for (int m = 0; m < 2; ++m) {
            const int base = bufo + aBase + (pair << 12) + (m << 11);
            dst[m][0] = *(const v4i*)(lds + base + colsw0);
            dst[m][1] = *(const v4i*)(lds + base + colsw1);
        }
    };
    auto ldBf = [&](int bufo) {      // all 4 n; s0 group first (P1 MFMAs consume s0 first)
#pragma unroll
        for (int n = 0; n < 4; ++n)
            bf[n][0] = *(const v4i*)(lds + 65536 + bufo + bBase + (n << 11) + colsw0);
#pragma unroll
        for (int n = 0; n < 4; ++n)
            bf[n][1] = *(const v4i*)(lds + 65536 + bufo + bBase + (n << 11) + colsw1);
    };

    // s-OUTER: first 8 MFMAs need only bf[.][0]; dep distance 8 per acc chain
#define MQ(afX, p) do {                                                           \
    _Pragma("unroll") for (int s_ = 0; s_ < 2; ++s_)                              \
    _Pragma("unroll") for (int m_ = 0; m_ < 2; ++m_)                              \
    _Pragma("unroll") for (int n_ = 0; n_ < 4; ++n_)                              \
        acc[((p) << 1) + m_][n_] = __builtin_amdgcn_mfma_i32_16x16x64_i8(         \
            afX[m_][s_], bf[n_][s_], acc[((p) << 1) + m_][n_], 0, 0, 0);          \
} while (0)

    // ---- prologue: stage tile0 (A+B, 8 loads), drain, read afA<-pair0 ----
    stage(Ab, 0,     0, 0);  stage(Ab, 0,     1, 0);
    stage(Bb, 65536, 0, 0);  stage(Bb, 65536, 1, 0);
    WAIT_VM(0);
    PH_BAR();
    SCHED_FENCE();
    ldAf(afA, 0, 0);

    const int nt = K >> 7;    // K-tiles of 128 B
    for (int t = 0; t < nt - 1; ++t) {
        const int b  = (t & 1) << 15;
        const int nb = (~t & 1) << 15;

        // region P1..P3: no barriers -- waves skew; per-wave order via reg dependences
        // P1: bf + afB<-pair1 | stage A(t+1) | MFMA pair0
        ldBf(b);
        ldAf(afB, b, 1);
        stage(Ab, nb, 0, t + 1);  stage(Ab, nb, 1, t + 1);
        PRIO1(); MQ(afA, 0); PRIO0();
        // P2: afA<-pair2 | stage B(t+1) | MFMA pair1
        ldAf(afA, b, 2);
        stage(Bb, 65536 + nb, 0, t + 1);  stage(Bb, 65536 + nb, 1, t + 1);
        PRIO1(); MQ(afB, 1); PRIO0();
        // P3: afB<-pair3 | MFMA pair2 | THE tile barrier
        ldAf(afB, b, 3);
        PRIO1(); MQ(afA, 2); PRIO0();
        WAIT_VM(0);       // staging of t+1 landed (read below + next P1's bf)
        WAIT_LGKM0();     // this wave's reads of buf b retired (WAR-safe re-staging)
        PH_BAR();
        SCHED_FENCE();
        // P4: afA<-pair0 of tile t+1 (buf nb) | MFMA pair3
        ldAf(afA, nb, 0);
        PRIO1(); MQ(afB, 3); PRIO0();
    }

    // ---- peeled last tile (no staging, no barrier needed) ----
    {
        const int b = ((nt - 1) & 1) << 15;
        ldBf(b);
        ldAf(afB, b, 1);
        PRIO1(); MQ(afA, 0); PRIO0();
        ldAf(afA, b, 2);
        PRIO1(); MQ(afB, 1); PRIO0();
        ldAf(afB, b, 3);
        PRIO1(); MQ(afA, 2); PRIO0();
        PRIO1(); MQ(afB, 3); PRIO0();
    }
#undef MQ

    // ---------------- epilogue: row-major store order, scales hoisted ----------------
    const float is = *is_p, os = *os_p;
    const float zp = (float)(*zp_p);
    const int colb = (bcol << 8) + (wc << 6) + lo16;
    float sc[4]; int bv[4];
#pragma unroll
    for (int n = 0; n < 4; ++n) {
        sc[n] = is * wscale[colb + (n << 4)] / os;
        bv[n] = bias[colb + (n << 4)];
    }
#pragma unroll
    for (int m = 0; m < 8; ++m) {
#pragma unroll
        for (int j = 0; j < 4; ++j) {
            const int row = (brow << 8) + (wr << 7) + (m << 4) + (hi << 2) + j;
            int* op = out + (size_t)row * Ncols + colb;
#pragma unroll
            for (int n = 0; n < 4; ++n) {
                float f = (float)(acc[m][n][j] + bv[n]) * sc[n] + zp;
                f = rintf(f);
                f = fminf(fmaxf(f, -128.f), 127.f);
                op[n << 4] = (int)f;
            }
        }
    }
}

// ---------------- fallback 128^2 2-barrier kernel (known-correct) ----------------
template <bool PACKED>
__global__ __launch_bounds__(256) void gemm_q8(
    const void* __restrict__ Ain, const void* __restrict__ Bin,
    const int* __restrict__ bias, const float* __restrict__ wscale,
    const float* __restrict__ is_p, const float* __restrict__ os_p,
    const int* __restrict__ zp_p,
    int* __restrict__ out, int Nrows, int K, int Ncols)
{
    __shared__ char Al[128 * 64];
    __shared__ char Bl[128 * 64];

    const int tid  = threadIdx.x;
    const int wid  = tid >> 6;
    const int lane = tid & 63;

    const int nbc = Ncols / 128;
    int swz = blockIdx.x;
    if ((gridDim.x & 7) == 0) {
        const int cpx = gridDim.x >> 3;
        swz = (blockIdx.x & 7) * cpx + (blockIdx.x >> 3);
    }
    const int brow = swz / nbc;
    const int bcol = swz % nbc;
    const int wr = wid >> 1, wc = wid & 1;

    v4i acc[4][4];
#pragma unroll
    for (int m = 0; m < 4; ++m)
#pragma unroll
        for (int n = 0; n < 4; ++n)
            acc[m][n] = (v4i){0, 0, 0, 0};

    const char* Ag = nullptr;
    const char* Bg = nullptr;
    if (PACKED) {
        Ag = (const char*)Ain + (size_t)(brow * 128 + wid * 32 + (lane >> 2)) * K + (lane & 3) * 16;
        Bg = (const char*)Bin + (size_t)(bcol * 128 + wid * 32 + (lane >> 2)) * K + (lane & 3) * 16;
    }
    char* aldst = Al + wid * 2048;
    char* bldst = Bl + wid * 2048;

    const int lo16 = lane & 15, hi = lane >> 4;
    const int aoff0 = (wr * 64 + lo16) * 64 + hi * 16;
    const int boff0 = (wc * 64 + lo16) * 64 + hi * 16;

    for (int k0 = 0; k0 < K; k0 += 64) {
        if (PACKED) {
            GLOAD16(Ag + k0,          aldst);
            GLOAD16(Ag + 16 * K + k0, aldst + 1024);
            GLOAD16(Bg + k0,          bldst);
            GLOAD16(Bg + 16 * K + k0, bldst + 1024);
        } else {
            const int row = tid >> 1, half = tid & 1;
            const int* sA = (const int*)Ain + (size_t)(brow * 128 + row) * K + k0 + half * 32;
            const int* sB = (const int*)Bin + (size_t)(bcol * 128 + row) * K + k0 + half * 32;
            int pa[8], pb[8];
#pragma unroll
            for (int j = 0; j < 8; ++j) {
                v4i va = reinterpret_cast<const v4i*>(sA)[j];
                v4i vb = reinterpret_cast<const v4i*>(sB)[j];
                pa[j] = pack4(va.x, va.y, va.z, va.w);
                pb[j] = pack4(vb.x, vb.y, vb.z, vb.w);
            }
            v4i* da = (v4i*)&Al[row * 64 + half * 32];
            da[0] = (v4i){pa[0], pa[1], pa[2], pa[3]};
            da[1] = (v4i){pa[4], pa[5], pa[6], pa[7]};
            v4i* db = (v4i*)&Bl[row * 64 + half * 32];
            db[0] = (v4i){pb[0], pb[1], pb[2], pb[3]};
            db[1] = (v4i){pb[4], pb[5], pb[6], pb[7]};
        }
        __syncthreads();

        v4i afr[4], bfr[4];
#pragma unroll
        for (int m = 0; m < 4; ++m)
            afr[m] = *(const v4i*)&Al[aoff0 + m * 16 * 64];
#pragma unroll
        for (int n = 0; n < 4; ++n)
            bfr[n] = *(const v4i*)&Bl[boff0 + n * 16 * 64];
#pragma unroll
        for (int m = 0; m < 4; ++m)
#pragma unroll
            for (int n = 0; n < 4; ++n)
                acc[m][n] = __builtin_amdgcn_mfma_i32_16x16x64_i8(afr[m], bfr[n], acc[m][n], 0, 0, 0);

        __syncthreads();
    }

    const float is = *is_p;
    const float os = *os_p;
    const float zp = (float)(*zp_p);
#pragma unroll
    for (int n = 0; n < 4; ++n) {
        const int col = bcol * 128 + wc * 64 + n * 16 + lo16;
        const float sc = is * wscale[col] / os;
        const int   bv = bias[col];
#pragma unroll
        for (int m = 0; m < 4; ++m) {
            const int row0 = brow * 128 + wr * 64 + m * 16 + hi * 4;
#pragma unroll
            for (int j = 0; j < 4; ++j) {
                float f = (float)(acc[m][n][j] + bv) * sc + zp;
                f = rintf(f);
                f = fminf(fmaxf(f, -128.f), 127.f);
                out[(size_t)(row0 + j) * Ncols + col] = (int)f;
            }
        }
    }
}

extern "C" void kernel_launch(void* const* d_in, const int* in_sizes, int n_in,
                              void* d_out, int out_size, void* d_ws, size_t ws_size,
                              hipStream_t stream) {
    const int*   x32    = (const int*)d_in[0];
    const int*   w32    = (const int*)d_in[1];
    const int*   bias   = (const int*)d_in[2];
    const float* wscale = (const float*)d_in[3];
    const float* isp    = (const float*)d_in[4];
    const float* osp    = (const float*)d_in[5];
    const int*   zpp    = (const int*)d_in[6];
    int* out = (int*)d_out;

    const int OUT = in_sizes[2];            // 4096
    const int K   = in_sizes[1] / OUT;      // 4096
    const int Nr  = in_sizes[0] / K;        // 8192

    const size_t need = (size_t)Nr * K + (size_t)OUT * K;

    if (ws_size >= need) {
        char* xpk = (char*)d_ws;
        char* wpk = xpk + (size_t)Nr * K;
        const int nx16 = (Nr * K) / 16;
        const int nw16 = (OUT * K) / 16;
        pack2_kernel<<<(nx16 + nw16 + 255) / 256, 256, 0, stream>>>(
            x32, (v4i*)xpk, nx16, w32, (v4i*)wpk, nw16);
        if ((Nr & 255) == 0 && (OUT & 255) == 0 && (K & 127) == 0 && (K >> 7) >= 2) {
            const int grid8 = (Nr / 256) * (OUT / 256);
            gemm_q8_mp<<<grid8, 512, 0, stream>>>(xpk, wpk, bias, wscale, isp, osp, zpp,
                                                  out, K, OUT);
        } else {
            const int grid = (Nr / 128) * (OUT / 128);
            gemm_q8<true><<<grid, 256, 0, stream>>>(xpk, wpk, bias, wscale, isp, osp, zpp,
                                                    out, Nr, K, OUT);
        }
    } else {
        const int grid = (Nr / 128) * (OUT / 128);
        gemm_q8<false><<<grid, 256, 0, stream>>>(x32, w32, bias, wscale, isp, osp, zpp,
                                                 out, Nr, K, OUT);
    }
}

// Round 11
// 169.928 us; speedup vs baseline: 1.7203x; 1.0106x over previous
//
#include <hip/hip_runtime.h>
#include <stdint.h>
#include <stddef.h>

typedef int v4i __attribute__((ext_vector_type(4)));

#define GLOAD16(gp, lp) __builtin_amdgcn_global_load_lds( \
    (const __attribute__((address_space(1))) void*)(gp),  \
    (__attribute__((address_space(3))) void*)(lp), 16, 0, 0)

#define PH_BAR()     __builtin_amdgcn_s_barrier()
#define WAIT_VM(n)   asm volatile("s_waitcnt vmcnt(" #n ")" ::: "memory")
#define WAIT_LGKM0() asm volatile("s_waitcnt lgkmcnt(0)" ::: "memory")
#define SCHED_FENCE() __builtin_amdgcn_sched_barrier(0)
#define PRIO1() __builtin_amdgcn_s_setprio(1)
#define PRIO0() __builtin_amdgcn_s_setprio(0)

static __device__ __forceinline__ int pack4(int a, int b, int c, int d) {
    return (a & 255) | ((b & 255) << 8) | ((c & 255) << 16) | (d << 24);
}

// ---------------- pack: int32 (values in [-128,127]) -> int8, both arrays ----------------
__global__ __launch_bounds__(256) void pack2_kernel(const int* __restrict__ srcA, v4i* __restrict__ dstA, int nA,
                                                    const int* __restrict__ srcB, v4i* __restrict__ dstB, int nB) {
    int i = blockIdx.x * blockDim.x + threadIdx.x;
    const int* src; v4i* dst;
    if (i < nA) { src = srcA; dst = dstA; }
    else { i -= nA; if (i >= nB) return; src = srcB; dst = dstB; }
    const v4i* s = reinterpret_cast<const v4i*>(src) + (size_t)i * 4;
    v4i v0 = s[0], v1 = s[1], v2 = s[2], v3 = s[3];
    v4i r;
    r.x = pack4(v0.x, v0.y, v0.z, v0.w);
    r.y = pack4(v1.x, v1.y, v1.z, v1.w);
    r.z = pack4(v2.x, v2.y, v2.z, v2.w);
    r.w = pack4(v3.x, v3.y, v3.z, v3.w);
    dst[i] = r;
}

// ====== 256x256 i8 GEMM: 1 barrier/K-tile, counted vmcnt, B staged 2 tiles ahead ======
// r9 + T4-proper: r9's P3 did WAIT_VM(0) -- a full staging drain welded to the barrier
// (B issued only 1 phase earlier -> every wave stalls at the barrier on its B loads, and
// the slowest gates all 8). Fix: B gets THREE buffers (A 2x32KB @0, B 3x32KB @65536;
// LDS = 160KB, full CU allotment, 1 block/CU as before). Stage A(t+1)@P1, B(t+2)@P2;
// P3-end WAIT_VM(4) drains [B(t+1),A(t+1)] (FIFO) and leaves B(t+2) IN FLIGHT across the
// barrier. B landing window: 4 phases (was 1). Cross-wave visibility of A(t+1)/B(t+1) =
// vm(4)+barrier at t.P3. WAR: B-buf of t+2 last read t-1.P1, retired by t-1.P3
// lgkm0+barrier, staged t.P2 (after it). A-buf WAR as r9. Requires nt >= 3.
__global__ __launch_bounds__(512, 1) void gemm_q8_mp(
    const char* __restrict__ Apk, const char* __restrict__ Bpk,
    const int* __restrict__ bias, const float* __restrict__ wscale,
    const float* __restrict__ is_p, const float* __restrict__ os_p,
    const int* __restrict__ zp_p,
    int* __restrict__ out, int K, int Ncols)
{
    __shared__ char lds[163840];

    const int tid  = threadIdx.x;
    const int wid  = tid >> 6;
    const int lane = tid & 63;
    const int l7 = lane & 7, l3 = lane >> 3;
    const int lo16 = lane & 15, hi = lane >> 4;

    // bijective XCD-aware swizzle (m204)
    int swz;
    {
        const int nwg = gridDim.x;
        const int q = nwg >> 3, r = nwg & 7;
        const int xcd = blockIdx.x & 7;
        const int base = (xcd < r) ? xcd * (q + 1) : r * (q + 1) + (xcd - r) * q;
        swz = base + (blockIdx.x >> 3);
    }
    const int nbc  = Ncols >> 8;
    const int brow = swz / nbc, bcol = swz % nbc;

    const int wr = wid >> 2, wc = wid & 3;   // 2M x 4N waves, 128x64 out each

    const char* Ab = Apk + (size_t)(brow * 256 + wid * 8 + l3) * K + ((l7 ^ l3) << 4);
    const char* Bb = Bpk + (size_t)(bcol * 256 + wid * 8 + l3) * K + ((l7 ^ l3) << 4);

    // ds_read: row*128 + slot*16, slot = chunk ^ (row&7); row&7 == l7 for all frag reads
    const int colsw0 = (hi ^ l7) << 4;
    const int colsw1 = colsw0 ^ 64;
    const int aBase = (wr << 14) + (lo16 << 7);          // + Abuf + pair<<12 + m<<11
    const int bBase = (wc << 13) + (lo16 << 7);          // + 65536 + Bbuf + n<<11

    v4i acc[8][4];
#pragma unroll
    for (int m = 0; m < 8; ++m)
#pragma unroll
        for (int n = 0; n < 4; ++n)
            acc[m][n] = (v4i){0, 0, 0, 0};

    v4i afA[2][2], afB[2][2], bf[4][2];

    auto stage = [&](const char* gb, int ldsOff, int h, int t) {
        const char* g = gb + (size_t)(h * 128) * K + ((size_t)t << 7);
        char* l = lds + (ldsOff + (h << 14) + (wid << 10));
        GLOAD16(g, l);
        GLOAD16(g + (size_t)64 * K, l + 8192);
    };
    auto ldAf = [&](v4i (&dst)[2][2], int bufo, int pair) {
#pragma unroll
        for (int m = 0; m < 2; ++m) {
            const int base = bufo + aBase + (pair << 12) + (m << 11);
            dst[m][0] = *(const v4i*)(lds + base + colsw0);
            dst[m][1] = *(const v4i*)(lds + base + colsw1);
        }
    };
    auto ldBf = [&](int bufo) {      // all 4 n; s0 group first (P1 MFMAs consume s0 first)
#pragma unroll
        for (int n = 0; n < 4; ++n)
            bf[n][0] = *(const v4i*)(lds + 65536 + bufo + bBase + (n << 11) + colsw0);
#pragma unroll
        for (int n = 0; n < 4; ++n)
            bf[n][1] = *(const v4i*)(lds + 65536 + bufo + bBase + (n << 11) + colsw1);
    };

    // s-OUTER: first 8 MFMAs need only bf[.][0]; dep distance 8 per acc chain
#define MQ(afX, p) do {                                                           \
    _Pragma("unroll") for (int s_ = 0; s_ < 2; ++s_)                              \
    _Pragma("unroll") for (int m_ = 0; m_ < 2; ++m_)                              \
    _Pragma("unroll") for (int n_ = 0; n_ < 4; ++n_)                              \
        acc[((p) << 1) + m_][n_] = __builtin_amdgcn_mfma_i32_16x16x64_i8(         \
            afX[m_][s_], bf[n_][s_], acc[((p) << 1) + m_][n_], 0, 0, 0);          \
} while (0)

    // ---- prologue: stage A0 (Abuf0), B0 (Bbuf0), B1 (Bbuf1); vm(4) leaves B1 in flight ----
    stage(Ab, 0,             0, 0);  stage(Ab, 0,             1, 0);
    stage(Bb, 65536,         0, 0);  stage(Bb, 65536,         1, 0);
    stage(Bb, 65536 + 32768, 0, 1);  stage(Bb, 65536 + 32768, 1, 1);
    WAIT_VM(4);          // A0+B0 landed; B1 (4) stays in flight
    PH_BAR();
    SCHED_FENCE();
    ldAf(afA, 0, 0);

    const int nt = K >> 7;    // K-tiles of 128 B (nt >= 3 guaranteed by dispatcher)
    int bcur = 0;             // B-buf byte offset of tile t: (t%3)*32768
    for (int t = 0; t < nt - 2; ++t) {
        const int bA  = (t & 1) << 15;
        const int nbA = (~t & 1) << 15;
        int bst = bcur + 65536; if (bst >= 98304) bst -= 98304;   // (t+2)%3 buf

        // P1: bf(t) + afB<-pair1 | stage A(t+1) | MFMA pair0
        ldBf(bcur);
        ldAf(afB, bA, 1);
        stage(Ab, nbA, 0, t + 1);  stage(Ab, nbA, 1, t + 1);
        PRIO1(); MQ(afA, 0); PRIO0();
        // P2: afA<-pair2 | stage B(t+2) two tiles ahead | MFMA pair1
        ldAf(afA, bA, 2);
        stage(Bb, 65536 + bst, 0, t + 2);  stage(Bb, 65536 + bst, 1, t + 2);
        PRIO1(); MQ(afB, 1); PRIO0();
        // P3: afB<-pair3 | MFMA pair2 | counted drain: [B(t+1),A(t+1)] out, B(t+2) stays
        ldAf(afB, bA, 3);
        PRIO1(); MQ(afA, 2); PRIO0();
        WAIT_VM(4);       // FIFO: drains B(t+1)+A(t+1); leaves B(t+2) in flight
        WAIT_LGKM0();     // this wave's reads of bufs b retired (WAR-safe re-staging)
        PH_BAR();
        SCHED_FENCE();
        // P4: afA<-pair0 of tile t+1 | MFMA pair3
        ldAf(afA, nbA, 0);
        PRIO1(); MQ(afB, 3); PRIO0();

        bcur += 32768; if (bcur >= 98304) bcur -= 98304;
    }

    // ---- peeled t = nt-2: stage only A(nt-1); full drain at P3 ----
    {
        const int t = nt - 2;
        const int bA  = (t & 1) << 15;
        const int nbA = (~t & 1) << 15;
        ldBf(bcur);
        ldAf(afB, bA, 1);
        stage(Ab, nbA, 0, t + 1);  stage(Ab, nbA, 1, t + 1);
        PRIO1(); MQ(afA, 0); PRIO0();
        ldAf(afA, bA, 2);
        PRIO1(); MQ(afB, 1); PRIO0();
        ldAf(afB, bA, 3);
        PRIO1(); MQ(afA, 2); PRIO0();
        WAIT_VM(0);       // drains B(nt-1) + A(nt-1)
        WAIT_LGKM0();
        PH_BAR();
        SCHED_FENCE();
        ldAf(afA, nbA, 0);
        PRIO1(); MQ(afB, 3); PRIO0();
        bcur += 32768; if (bcur >= 98304) bcur -= 98304;
    }
    // ---- peeled t = nt-1: no staging, no barrier ----
    {
        const int bA = ((nt - 1) & 1) << 15;
        ldBf(bcur);
        ldAf(afB, bA, 1);
        PRIO1(); MQ(afA, 0); PRIO0();
        ldAf(afA, bA, 2);
        PRIO1(); MQ(afB, 1); PRIO0();
        ldAf(afB, bA, 3);
        PRIO1(); MQ(afA, 2); PRIO0();
        PRIO1(); MQ(afB, 3); PRIO0();
    }
#undef MQ

    // ---------------- epilogue: row-major store order, scales hoisted ----------------
    const float is = *is_p, os = *os_p;
    const float zp = (float)(*zp_p);
    const int colb = (bcol << 8) + (wc << 6) + lo16;
    float sc[4]; int bv[4];
#pragma unroll
    for (int n = 0; n < 4; ++n) {
        sc[n] = is * wscale[colb + (n << 4)] / os;
        bv[n] = bias[colb + (n << 4)];
    }
#pragma unroll
    for (int m = 0; m < 8; ++m) {
#pragma unroll
        for (int j = 0; j < 4; ++j) {
            const int row = (brow << 8) + (wr << 7) + (m << 4) + (hi << 2) + j;
            int* op = out + (size_t)row * Ncols + colb;
#pragma unroll
            for (int n = 0; n < 4; ++n) {
                float f = (float)(acc[m][n][j] + bv[n]) * sc[n] + zp;
                f = rintf(f);
                f = fminf(fmaxf(f, -128.f), 127.f);
                op[n << 4] = (int)f;
            }
        }
    }
}

// ---------------- fallback 128^2 2-barrier kernel (known-correct) ----------------
template <bool PACKED>
__global__ __launch_bounds__(256) void gemm_q8(
    const void* __restrict__ Ain, const void* __restrict__ Bin,
    const int* __restrict__ bias, const float* __restrict__ wscale,
    const float* __restrict__ is_p, const float* __restrict__ os_p,
    const int* __restrict__ zp_p,
    int* __restrict__ out, int Nrows, int K, int Ncols)
{
    __shared__ char Al[128 * 64];
    __shared__ char Bl[128 * 64];

    const int tid  = threadIdx.x;
    const int wid  = tid >> 6;
    const int lane = tid & 63;

    const int nbc = Ncols / 128;
    int swz = blockIdx.x;
    if ((gridDim.x & 7) == 0) {
        const int cpx = gridDim.x >> 3;
        swz = (blockIdx.x & 7) * cpx + (blockIdx.x >> 3);
    }
    const int brow = swz / nbc;
    const int bcol = swz % nbc;
    const int wr = wid >> 1, wc = wid & 1;

    v4i acc[4][4];
#pragma unroll
    for (int m = 0; m < 4; ++m)
#pragma unroll
        for (int n = 0; n < 4; ++n)
            acc[m][n] = (v4i){0, 0, 0, 0};

    const char* Ag = nullptr;
    const char* Bg = nullptr;
    if (PACKED) {
        Ag = (const char*)Ain + (size_t)(brow * 128 + wid * 32 + (lane >> 2)) * K + (lane & 3) * 16;
        Bg = (const char*)Bin + (size_t)(bcol * 128 + wid * 32 + (lane >> 2)) * K + (lane & 3) * 16;
    }
    char* aldst = Al + wid * 2048;
    char* bldst = Bl + wid * 2048;

    const int lo16 = lane & 15, hi = lane >> 4;
    const int aoff0 = (wr * 64 + lo16) * 64 + hi * 16;
    const int boff0 = (wc * 64 + lo16) * 64 + hi * 16;

    for (int k0 = 0; k0 < K; k0 += 64) {
        if (PACKED) {
            GLOAD16(Ag + k0,          aldst);
            GLOAD16(Ag + 16 * K + k0, aldst + 1024);
            GLOAD16(Bg + k0,          bldst);
            GLOAD16(Bg + 16 * K + k0, bldst + 1024);
        } else {
            const int row = tid >> 1, half = tid & 1;
            const int* sA = (const int*)Ain + (size_t)(brow * 128 + row) * K + k0 + half * 32;
            const int* sB = (const int*)Bin + (size_t)(bcol * 128 + row) * K + k0 + half * 32;
            int pa[8], pb[8];
#pragma unroll
            for (int j = 0; j < 8; ++j) {
                v4i va = reinterpret_cast<const v4i*>(sA)[j];
                v4i vb = reinterpret_cast<const v4i*>(sB)[j];
                pa[j] = pack4(va.x, va.y, va.z, va.w);
                pb[j] = pack4(vb.x, vb.y, vb.z, vb.w);
            }
            v4i* da = (v4i*)&Al[row * 64 + half * 32];
            da[0] = (v4i){pa[0], pa[1], pa[2], pa[3]};
            da[1] = (v4i){pa[4], pa[5], pa[6], pa[7]};
            v4i* db = (v4i*)&Bl[row * 64 + half * 32];
            db[0] = (v4i){pb[0], pb[1], pb[2], pb[3]};
            db[1] = (v4i){pb[4], pb[5], pb[6], pb[7]};
        }
        __syncthreads();

        v4i afr[4], bfr[4];
#pragma unroll
        for (int m = 0; m < 4; ++m)
            afr[m] = *(const v4i*)&Al[aoff0 + m * 16 * 64];
#pragma unroll
        for (int n = 0; n < 4; ++n)
            bfr[n] = *(const v4i*)&Bl[boff0 + n * 16 * 64];
#pragma unroll
        for (int m = 0; m < 4; ++m)
#pragma unroll
            for (int n = 0; n < 4; ++n)
                acc[m][n] = __builtin_amdgcn_mfma_i32_16x16x64_i8(afr[m], bfr[n], acc[m][n], 0, 0, 0);

        __syncthreads();
    }

    const float is = *is_p;
    const float os = *os_p;
    const float zp = (float)(*zp_p);
#pragma unroll
    for (int n = 0; n < 4; ++n) {
        const int col = bcol * 128 + wc * 64 + n * 16 + lo16;
        const float sc = is * wscale[col] / os;
        const int   bv = bias[col];
#pragma unroll
        for (int m = 0; m < 4; ++m) {
            const int row0 = brow * 128 + wr * 64 + m * 16 + hi * 4;
#pragma unroll
            for (int j = 0; j < 4; ++j) {
                float f = (float)(acc[m][n][j] + bv) * sc + zp;
                f = rintf(f);
                f = fminf(fmaxf(f, -128.f), 127.f);
                out[(size_t)(row0 + j) * Ncols + col] = (int)f;
            }
        }
    }
}

extern "C" void kernel_launch(void* const* d_in, const int* in_sizes, int n_in,
                              void* d_out, int out_size, void* d_ws, size_t ws_size,
                              hipStream_t stream) {
    const int*   x32    = (const int*)d_in[0];
    const int*   w32    = (const int*)d_in[1];
    const int*   bias   = (const int*)d_in[2];
    const float* wscale = (const float*)d_in[3];
    const float* isp    = (const float*)d_in[4];
    const float* osp    = (const float*)d_in[5];
    const int*   zpp    = (const int*)d_in[6];
    int* out = (int*)d_out;

    const int OUT = in_sizes[2];            // 4096
    const int K   = in_sizes[1] / OUT;      // 4096
    const int Nr  = in_sizes[0] / K;        // 8192

    const size_t need = (size_t)Nr * K + (size_t)OUT * K;

    if (ws_size >= need) {
        char* xpk = (char*)d_ws;
        char* wpk = xpk + (size_t)Nr * K;
        const int nx16 = (Nr * K) / 16;
        const int nw16 = (OUT * K) / 16;
        pack2_kernel<<<(nx16 + nw16 + 255) / 256, 256, 0, stream>>>(
            x32, (v4i*)xpk, nx16, w32, (v4i*)wpk, nw16);
        if ((Nr & 255) == 0 && (OUT & 255) == 0 && (K & 127) == 0 && (K >> 7) >= 3) {
            const int grid8 = (Nr / 256) * (OUT / 256);
            gemm_q8_mp<<<grid8, 512, 0, stream>>>(xpk, wpk, bias, wscale, isp, osp, zpp,
                                                  out, K, OUT);
        } else {
            const int grid = (Nr / 128) * (OUT / 128);
            gemm_q8<true><<<grid, 256, 0, stream>>>(xpk, wpk, bias, wscale, isp, osp, zpp,
                                                    out, Nr, K, OUT);
        }
    } else {
        const int grid = (Nr / 128) * (OUT / 128);
        gemm_q8<false><<<grid, 256, 0, stream>>>(x32, w32, bias, wscale, isp, osp, zpp,
                                                 out, Nr, K, OUT);
    }
}